// Round 1
// baseline (476.395 us; speedup 1.0000x reference)
//
#include <hip/hip_runtime.h>
#include <math.h>

#define NN 50000
#define EE 800000
#define AIN 256
#define OH 128

#define NTOT  (2 * NN)        // combined node ids: set0 = [0,NN), set1 = [NN,2NN)
#define NB    391             // buckets of 256 nodes
#define CAP   5120            // per-bucket stage capacity (mean 4092, +16 sigma)

typedef __attribute__((ext_vector_type(8))) short bf16x8;
typedef __attribute__((ext_vector_type(4))) float f32x4;

static __device__ __forceinline__ unsigned short f2bf(float f) {
    union { float f; unsigned int u; } v; v.f = f;
    return (unsigned short)((v.u + 0x7FFFu + ((v.u >> 16) & 1u)) >> 16);
}
static __device__ __forceinline__ float bflo(unsigned int u) { return __uint_as_float(u << 16); }
static __device__ __forceinline__ float bfhi(unsigned int u) { return __uint_as_float(u & 0xFFFF0000u); }

// ---------------------------------------------------------------------------
__global__ __launch_bounds__(256) void cvt_x_k(const float* __restrict__ x, unsigned short* __restrict__ xb)
{
    const int i = blockIdx.x * 256 + threadIdx.x;
    if (i >= NN * AIN / 4) return;
    const float4 v = ((const float4*)x)[i];
    ushort4 o;
    o.x = f2bf(v.x); o.y = f2bf(v.y); o.z = f2bf(v.z); o.w = f2bf(v.w);
    ((ushort4*)xb)[i] = o;
}

__global__ __launch_bounds__(256) void cvt_w_k(
    const float* __restrict__ Wq, const float* __restrict__ Wk,
    const float* __restrict__ Wv, const float* __restrict__ Wf,
    const float* __restrict__ Wo, unsigned short* __restrict__ Wt,
    unsigned short* __restrict__ Waot)
{
    const int n = blockIdx.x;
    const int k = threadIdx.x;
    if (n < 512) {
        const float* W = (n < 128) ? Wq : (n < 256) ? Wk : (n < 384) ? Wv : Wf;
        Wt[(size_t)n * 256 + k] = f2bf(W[(size_t)k * OH + (n & 127)]);
    } else {
        if (k < 128) Waot[(size_t)(n - 512) * 128 + k] = f2bf(Wo[(size_t)k * OH + (n - 512)]);
    }
}

// ---------------------------------------------------------------------------
// Fused QKV+FFN GEMM, bf16 MFMA 16x16x32. 128x128 tile, BK=32, 4 waves.
// y=0 -> q (fp32 out), y=1 -> k (bf16 into kv col 0), y=2 -> v (bf16 kv col
// 128), y=3 -> ffn (bf16).
// ---------------------------------------------------------------------------
__global__ __launch_bounds__(256) void qkvf_mfma_k(
    const unsigned short* __restrict__ xb,
    const unsigned short* __restrict__ Wt,
    const float* __restrict__ bq, const float* __restrict__ bk,
    const float* __restrict__ bv, const float* __restrict__ bf,
    float* __restrict__ qf, unsigned short* __restrict__ kv,
    unsigned short* __restrict__ ffnb, int M)
{
    __shared__ unsigned short As[128][40];
    __shared__ unsigned short Bs[128][40];
    const int tid  = threadIdx.x;
    const int lane = tid & 63;
    const int wave = tid >> 6;
    const int wr = wave >> 1, wc = wave & 1;
    const int quad = lane >> 4, m16 = lane & 15;
    const int row0 = blockIdx.x * 128;
    const int col0 = blockIdx.y * 128;

    f32x4 acc[4][4];
    #pragma unroll
    for (int i = 0; i < 4; ++i)
        #pragma unroll
        for (int j = 0; j < 4; ++j) acc[i][j] = 0.f;

    const int lr  = tid >> 1;
    const int lkh = (tid & 1) * 16;

    for (int kt = 0; kt < 256; kt += 32) {
        uint4 a0 = {0,0,0,0}, a1 = {0,0,0,0};
        const int grow = row0 + lr;
        if (grow < M) {
            const uint4* p = (const uint4*)(xb + (size_t)grow * 256 + kt + lkh);
            a0 = p[0]; a1 = p[1];
        }
        *(uint4*)&As[lr][lkh]     = a0;
        *(uint4*)&As[lr][lkh + 8] = a1;
        const uint4* wp = (const uint4*)(Wt + (size_t)(col0 + lr) * 256 + kt + lkh);
        *(uint4*)&Bs[lr][lkh]     = wp[0];
        *(uint4*)&Bs[lr][lkh + 8] = wp[1];
        __syncthreads();
        bf16x8 af[4], bfr[4];
        #pragma unroll
        for (int t = 0; t < 4; ++t) af[t]  = *(const bf16x8*)&As[wr * 64 + t * 16 + m16][quad * 8];
        #pragma unroll
        for (int t = 0; t < 4; ++t) bfr[t] = *(const bf16x8*)&Bs[wc * 64 + t * 16 + m16][quad * 8];
        #pragma unroll
        for (int i = 0; i < 4; ++i)
            #pragma unroll
            for (int j = 0; j < 4; ++j)
                acc[i][j] = __builtin_amdgcn_mfma_f32_16x16x32_bf16(af[i], bfr[j], acc[i][j], 0, 0, 0);
        __syncthreads();
    }

    const int y = blockIdx.y;
    const float* bias = (y == 0) ? bq : (y == 1) ? bk : (y == 2) ? bv : bf;

    if (y == 0) {
        #pragma unroll
        for (int i = 0; i < 4; ++i)
            #pragma unroll
            for (int j = 0; j < 4; ++j) {
                const int col = wc * 64 + j * 16 + m16;
                const float b = bias[col];
                #pragma unroll
                for (int r = 0; r < 4; ++r) {
                    const int row = row0 + wr * 64 + i * 16 + quad * 4 + r;
                    if (row < M) qf[(size_t)row * 128 + col] = acc[i][j][r] + b;
                }
            }
    } else {
        unsigned short* obase = (y == 3) ? ffnb : kv;
        const int ostride = (y == 3) ? 128 : 256;
        const int ocol    = (y == 2) ? 128 : 0;
        #pragma unroll
        for (int i = 0; i < 4; ++i)
            #pragma unroll
            for (int j = 0; j < 4; ++j) {
                const int col = wc * 64 + j * 16 + m16;
                const float b = bias[col];
                #pragma unroll
                for (int r = 0; r < 4; ++r) {
                    const int row = row0 + wr * 64 + i * 16 + quad * 4 + r;
                    if (row < M) obase[(size_t)row * ostride + ocol + col] = f2bf(acc[i][j][r] + b);
                }
            }
    }
}

// ---------------------------------------------------------------------------
// Pass 1: bin edges into NB buckets of 256 nodes. Stage record:
// x = f32 feat bits, y = (src << 8) | (nid & 255).
// ---------------------------------------------------------------------------
__global__ __launch_bounds__(256) void binpass_k(
    const int* __restrict__ dst0, const int* __restrict__ dst1,
    const int* __restrict__ src0, const int* __restrict__ src1,
    const float* __restrict__ feat0, const float* __restrict__ feat1,
    int* __restrict__ cursor, uint2* __restrict__ stage)
{
    __shared__ int hcnt[NB], blkbase[NB], lcur[NB];
    const int tid = threadIdx.x;
    const long base = (long)blockIdx.x * 8192;

    for (int i = tid; i < NB; i += 256) { hcnt[i] = 0; lcur[i] = 0; }
    __syncthreads();

    for (int i = tid; i < 8192; i += 256) {
        const long e = base + i;
        if (e < 2L * EE) {
            const int nid = (e < EE) ? dst0[e] : NN + dst1[e - EE];
            atomicAdd(&hcnt[nid >> 8], 1);
        }
    }
    __syncthreads();
    for (int i = tid; i < NB; i += 256)
        if (hcnt[i]) blkbase[i] = atomicAdd(&cursor[i], hcnt[i]);
    __syncthreads();

    for (int i = tid; i < 8192; i += 256) {
        const long e = base + i;
        if (e < 2L * EE) {
            const bool a = (e < EE);
            const int ee = a ? (int)e : (int)(e - EE);
            const int nid = a ? dst0[ee] : NN + dst1[ee];
            const int s = a ? src0[ee] : src1[ee];
            const float f = a ? feat0[(size_t)ee * 2] : feat1[(size_t)ee * 2];
            const int bk = nid >> 8;
            const int r = atomicAdd(&lcur[bk], 1);
            uint2 rec;
            rec.x = __float_as_uint(f);
            rec.y = ((unsigned int)s << 8) | (unsigned int)(nid & 255);
            stage[(size_t)bk * CAP + blkbase[bk] + r] = rec;
        }
    }
}

__global__ __launch_bounds__(512) void bscan_k(const int* __restrict__ cursor, int* __restrict__ bbase)
{
    __shared__ int part[512];
    const int t = threadIdx.x;
    const int v = (t < NB) ? cursor[t] : 0;
    part[t] = v;
    __syncthreads();
    for (int st = 1; st < 512; st <<= 1) {
        int u = (t >= st) ? part[t - st] : 0;
        __syncthreads();
        part[t] += u;
        __syncthreads();
    }
    if (t < NB) bbase[t] = part[t] - v;
}

// ---------------------------------------------------------------------------
// Pass 2: one block per bucket. Sort bucket records into node order; emit
// erec = {src, f32 feat} plus off/deg per node.
// ---------------------------------------------------------------------------
__global__ __launch_bounds__(256) void sortpass_k(
    const uint2* __restrict__ stage, const int* __restrict__ cursor,
    const int* __restrict__ bbase, uint2* __restrict__ erec,
    int* __restrict__ off, int* __restrict__ deg)
{
    __shared__ int h[256], eb[256], cur[256];
    const int b = blockIdx.x;
    const int t = threadIdx.x;
    const int cntb = cursor[b];
    const int obase = bbase[b];
    const uint2* sb = stage + (size_t)b * CAP;

    h[t] = 0; cur[t] = 0;
    __syncthreads();
    for (int i = t; i < cntb; i += 256) atomicAdd(&h[(int)(sb[i].y & 255u)], 1);
    __syncthreads();
    eb[t] = h[t];
    __syncthreads();
    for (int st = 1; st < 256; st <<= 1) {
        int u = (t >= st) ? eb[t - st] : 0;
        __syncthreads();
        eb[t] += u;
        __syncthreads();
    }
    const int incl = eb[t];
    __syncthreads();
    eb[t] = incl - h[t];          // exclusive
    __syncthreads();

    const int nid = b * 256 + t;
    if (nid < NTOT) {
        off[nid] = obase + eb[t];
        deg[nid] = h[t];
    }

    for (int i = t; i < cntb; i += 256) {
        const uint2 r = sb[i];
        const int loc = (int)(r.y & 255u);
        const int rk = atomicAdd(&cur[loc], 1);
        uint2 o;
        o.x = r.y >> 8;    // src
        o.y = r.x;         // f32 feat bits
        erec[obase + eb[loc] + rk] = o;
    }
}

// ---------------------------------------------------------------------------
// Aggregation, both edge sets in one dispatch: one wave per combined node id.
// Lane layout: g = lane>>4 is the edge slot (4 edges in flight per wave),
// d16 = lane&15 is the dim-block (owns dims [d16*8, d16*8+8), i.e. 16B of
// the 256B kv row). Head structure (H=4, D=32) maps to d16>>2, so the dot
// reduce is just 2 shfl_xor levels (4 lanes = 1 head) and the per-head score
// is already resident in every lane that accumulates that head's V dims —
// no score-broadcast shuffles at all. K/V arrive as 2 dwordx4 per batch
// (single address, +256B imm offset for V), software-prefetched one batch
// ahead. Cross-slot accumulator combine is a once-per-node epilogue.
// q fp32, k/v bf16, feat fp32.
// ---------------------------------------------------------------------------
__global__ __launch_bounds__(256) void aggregate_k(
    const float* __restrict__ qf, const unsigned short* __restrict__ kv,
    const uint2* __restrict__ erec,
    const int* __restrict__ off, const int* __restrict__ deg,
    unsigned short* __restrict__ att)
{
    const int nid = blockIdx.x * 4 + (threadIdx.x >> 6);
    if (nid >= NTOT) return;
    const int n = (nid >= NN) ? nid - NN : nid;
    const int lane = threadIdx.x & 63;
    const int g   = lane >> 4;     // edge slot 0..3
    const int d16 = lane & 15;     // dim-block: dims [d16*8, d16*8+8)
    const int start = off[nid];
    const int count = deg[nid];

    // q: my 8 dims as fp32 (groups duplicate the read -> same cache lines)
    const float4* qp = (const float4*)(qf + (size_t)n * 128 + d16 * 8);
    const float4 qa = qp[0];
    const float4 qb = qp[1];

    float a0 = 0.f, a1 = 0.f, a2 = 0.f, a3 = 0.f;
    float a4 = 0.f, a5 = 0.f, a6 = 0.f, a7 = 0.f;
    float zp = 0.f;
    const float SCALE = 0.088388347648318447f;  // 1/sqrt(128)
    const unsigned short* kvl = kv + d16 * 8;   // lane-fixed dim offset

    for (int base = 0; base < count; base += 64) {
        const int m = min(64, count - base);
        const uint2 rr = erec[start + base + min(lane, m - 1)];
        // prefetch batch 0 (dead slots read the clamped record: valid addr)
        int src = __shfl((int)rr.x, g);
        const uint4* p0 = (const uint4*)(kvl + (size_t)src * 256);
        uint4 kc = p0[0];
        uint4 vc = p0[16];     // +128 us = +256B: v half of the row
        for (int j0 = 0; j0 < m; j0 += 4) {
            const uint4 kk = kc, vv = vc;
            const float f = __int_as_float(__shfl((int)rr.y, j0 + g));
            const int jn = j0 + 4;
            if (jn < m) {      // uniform branch: prefetch next batch
                src = __shfl((int)rr.x, jn + g);
                const uint4* pn = (const uint4*)(kvl + (size_t)src * 256);
                kc = pn[0];
                vc = pn[16];
            }
            // my 8-dim partial of this head's dot
            float p =        bflo(kk.x) * qa.x;
            p = fmaf(bfhi(kk.x), qa.y, p);
            p = fmaf(bflo(kk.y), qa.z, p);
            p = fmaf(bfhi(kk.y), qa.w, p);
            p = fmaf(bflo(kk.z), qb.x, p);
            p = fmaf(bfhi(kk.z), qb.y, p);
            p = fmaf(bflo(kk.w), qb.z, p);
            p = fmaf(bfhi(kk.w), qb.w, p);
            // head reduce: 4 lanes (d16 within the same head) = 32 dims
            p += __shfl_xor(p, 1);
            p += __shfl_xor(p, 2);
            float sc = __expf(fminf(5.f, fmaxf(-5.f, p * f * SCALE)));
            sc = (j0 + g < m) ? sc : 0.f;
            zp += sc;          // per-lane: my head's z over my slot's edges
            a0 = fmaf(bflo(vv.x), sc, a0);
            a1 = fmaf(bfhi(vv.x), sc, a1);
            a2 = fmaf(bflo(vv.y), sc, a2);
            a3 = fmaf(bfhi(vv.y), sc, a3);
            a4 = fmaf(bflo(vv.z), sc, a4);
            a5 = fmaf(bfhi(vv.z), sc, a5);
            a6 = fmaf(bflo(vv.w), sc, a6);
            a7 = fmaf(bfhi(vv.w), sc, a7);
        }
    }

    // combine the 4 edge slots (lane bits 4,5)
    float z = zp;
    z += __shfl_xor(z, 16);
    z += __shfl_xor(z, 32);
    a0 += __shfl_xor(a0, 16); a0 += __shfl_xor(a0, 32);
    a1 += __shfl_xor(a1, 16); a1 += __shfl_xor(a1, 32);
    a2 += __shfl_xor(a2, 16); a2 += __shfl_xor(a2, 32);
    a3 += __shfl_xor(a3, 16); a3 += __shfl_xor(a3, 32);
    a4 += __shfl_xor(a4, 16); a4 += __shfl_xor(a4, 32);
    a5 += __shfl_xor(a5, 16); a5 += __shfl_xor(a5, 32);
    a6 += __shfl_xor(a6, 16); a6 += __shfl_xor(a6, 32);
    a7 += __shfl_xor(a7, 16); a7 += __shfl_xor(a7, 32);

    const float inv = 1.f / (z + 1.f);   // per-head z (head = d16>>2)
    // slot g writes dims d16*8 + 2g, 2g+1 (static-index selects, no scratch)
    const float e0 = (g & 1) ? a2 : a0;
    const float e1 = (g & 1) ? a3 : a1;
    const float e2 = (g & 1) ? a6 : a4;
    const float e3 = (g & 1) ? a7 : a5;
    const float ax = ((g & 2) ? e2 : e0) * inv;
    const float ay = ((g & 2) ? e3 : e1) * inv;
    const unsigned int o = ((unsigned int)f2bf(ay) << 16) | (unsigned int)f2bf(ax);
    *(unsigned int*)(att + (size_t)nid * 128 + d16 * 8 + g * 2) = o;
}

// ---------------------------------------------------------------------------
// Output GEMM for both sets (blockIdx.y). LN epilogue fully in fp32 registers.
// ---------------------------------------------------------------------------
__global__ __launch_bounds__(256) void attn_out_mfma_k(
    const unsigned short* __restrict__ attAll, const unsigned short* __restrict__ Wt,
    const float* __restrict__ bo, const unsigned short* __restrict__ ffnb,
    const float* __restrict__ g, const float* __restrict__ bln,
    float* __restrict__ Yall, int M)
{
    __shared__ unsigned short As[128][40];
    __shared__ unsigned short Bs[128][40];
    __shared__ float rsum[2][128], rsq[2][128];
    __shared__ float meanar[128], invar[128];

    const unsigned short* att = attAll + (size_t)blockIdx.y * NN * 128;
    float* Y = Yall + (size_t)blockIdx.y * NN * 128;

    const int tid  = threadIdx.x;
    const int lane = tid & 63;
    const int wave = tid >> 6;
    const int wr = wave >> 1, wc = wave & 1;
    const int quad = lane >> 4, m16 = lane & 15;
    const int row0 = blockIdx.x * 128;

    f32x4 acc[4][4];
    #pragma unroll
    for (int i = 0; i < 4; ++i)
        #pragma unroll
        for (int j = 0; j < 4; ++j) acc[i][j] = 0.f;

    const int lr  = tid >> 1;
    const int lkh = (tid & 1) * 16;

    for (int kt = 0; kt < 128; kt += 32) {
        uint4 a0 = {0,0,0,0}, a1 = {0,0,0,0};
        const int grow = row0 + lr;
        if (grow < M) {
            const uint4* p = (const uint4*)(att + (size_t)grow * 128 + kt + lkh);
            a0 = p[0]; a1 = p[1];
        }
        *(uint4*)&As[lr][lkh]     = a0;
        *(uint4*)&As[lr][lkh + 8] = a1;
        const uint4* wp = (const uint4*)(Wt + (size_t)lr * 128 + kt + lkh);
        *(uint4*)&Bs[lr][lkh]     = wp[0];
        *(uint4*)&Bs[lr][lkh + 8] = wp[1];
        __syncthreads();
        bf16x8 af[4], bfr[4];
        #pragma unroll
        for (int t = 0; t < 4; ++t) af[t]  = *(const bf16x8*)&As[wr * 64 + t * 16 + m16][quad * 8];
        #pragma unroll
        for (int t = 0; t < 4; ++t) bfr[t] = *(const bf16x8*)&Bs[wc * 64 + t * 16 + m16][quad * 8];
        #pragma unroll
        for (int i = 0; i < 4; ++i)
            #pragma unroll
            for (int j = 0; j < 4; ++j)
                acc[i][j] = __builtin_amdgcn_mfma_f32_16x16x32_bf16(af[i], bfr[j], acc[i][j], 0, 0, 0);
        __syncthreads();
    }

    // ah = C + bo + ffn (fp32 in regs); per-row partial sums
    #pragma unroll
    for (int i = 0; i < 4; ++i) {
        #pragma unroll
        for (int r = 0; r < 4; ++r) {
            const int rl = wr * 64 + i * 16 + quad * 4 + r;
            const int grow = row0 + rl;
            float s = 0.f, q = 0.f;
            #pragma unroll
            for (int j = 0; j < 4; ++j) {
                const int col = wc * 64 + j * 16 + m16;
                float v = acc[i][j][r] + bo[col];
                if (grow < M) v += bflo(ffnb[(size_t)grow * 128 + col]);
                acc[i][j][r] = v;
                s += v; q += v * v;
            }
            #pragma unroll
            for (int mm = 1; mm <= 8; mm <<= 1) {
                s += __shfl_xor(s, mm, 16);
                q += __shfl_xor(q, mm, 16);
            }
            if (m16 == 0) { rsum[wc][rl] = s; rsq[wc][rl] = q; }
        }
    }
    __syncthreads();
    if (tid < 128) {
        const float s = rsum[0][tid] + rsum[1][tid];
        const float q = rsq[0][tid] + rsq[1][tid];
        const float mean = s * (1.f / 128.f);
        const float var  = q * (1.f / 128.f) - mean * mean;
        meanar[tid] = mean;
        invar[tid]  = rsqrtf(fmaxf(var, 0.f) + 1e-5f);
    }
    __syncthreads();

    #pragma unroll
    for (int i = 0; i < 4; ++i) {
        #pragma unroll
        for (int j = 0; j < 4; ++j) {
            const int col = wc * 64 + j * 16 + m16;
            const float gv = g[col], lv = bln[col];
            #pragma unroll
            for (int r = 0; r < 4; ++r) {
                const int rl = wr * 64 + i * 16 + quad * 4 + r;
                const int grow = row0 + rl;
                if (grow < M) {
                    const float v = acc[i][j][r];
                    Y[(size_t)grow * 128 + col] = v + (v - meanar[rl]) * invar[rl] * gv + lv;
                }
            }
        }
    }
}

// ---------------------------------------------------------------------------
extern "C" void kernel_launch(void* const* d_in, const int* in_sizes, int n_in,
                              void* d_out, int out_size, void* d_ws, size_t ws_size,
                              hipStream_t stream) {
    const float* x99   = (const float*)d_in[2];
    const float* feat0 = (const float*)d_in[3];
    const float* feat1 = (const float*)d_in[4];
    const float* Waq   = (const float*)d_in[10];
    const float* Wak   = (const float*)d_in[11];
    const float* Wav   = (const float*)d_in[12];
    const float* Wao   = (const float*)d_in[13];
    const float* Waffn = (const float*)d_in[14];
    const float* baq   = (const float*)d_in[20];
    const float* bak   = (const float*)d_in[21];
    const float* bav   = (const float*)d_in[22];
    const float* bao   = (const float*)d_in[23];
    const float* baffn = (const float*)d_in[24];
    const float* aln_b = (const float*)d_in[26];
    const float* aln_g = (const float*)d_in[28];
    const int* src0 = (const int*)d_in[29];
    const int* dst0 = (const int*)d_in[30];
    const int* src1 = (const int*)d_in[31];
    const int* dst1 = (const int*)d_in[32];

    // workspace (~116 MB)
    unsigned short* xb   = (unsigned short*)d_ws;                 // NN*256 us
    float*          qf   = (float*)(xb + (size_t)NN * 256);       // NN*128 f32
    unsigned short* kv   = (unsigned short*)(qf + (size_t)NN * 128);  // NN*256 us
    unsigned short* ffnb = kv   + (size_t)NN * 256;               // NN*128 us
    unsigned short* att  = ffnb + (size_t)NN * 128;               // 2*NN*128 us
    unsigned short* Wt   = att  + (size_t)NTOT * 128;             // 512*256 us
    unsigned short* Waot = Wt   + (size_t)512 * 256;              // 128*128 us
    int* cursor = (int*)(Waot + 128 * 128);                       // NB
    int* bbase  = cursor + NB;                                    // NB
    int* off    = bbase + NB;                                     // NTOT
    int* deg    = off + NTOT;                                     // NTOT

    float* out = (float*)d_out;
    // stage (16.0 MB) + erec (12.8 MB) parked in d_out; both are fully
    // consumed (sortpass, aggregate) before attn_out writes d_out.
    uint2* stage = (uint2*)d_out;                                 // NB*CAP
    uint2* erec  = stage + (size_t)NB * CAP;                      // 2*EE

    cvt_x_k<<<(NN * AIN / 4 + 255) / 256, 256, 0, stream>>>(x99, xb);
    cvt_w_k<<<640, 256, 0, stream>>>(Waq, Wak, Wav, Waffn, Wao, Wt, Waot);

    const int mtiles = (NN + 127) / 128;   // 391
    qkvf_mfma_k<<<dim3(mtiles, 4), 256, 0, stream>>>(xb, Wt, baq, bak, bav, baffn, qf, kv, ffnb, NN);

    hipMemsetAsync(cursor, 0, NB * sizeof(int), stream);
    binpass_k<<<(2 * EE + 8191) / 8192, 256, 0, stream>>>(
        dst0, dst1, src0, src1, feat0, feat1, cursor, stage);
    bscan_k<<<1, 512, 0, stream>>>(cursor, bbase);
    sortpass_k<<<NB, 256, 0, stream>>>(stage, cursor, bbase, erec, off, deg);

    aggregate_k<<<(NTOT + 3) / 4, 256, 0, stream>>>(qf, kv, erec, off, deg, att);
    attn_out_mfma_k<<<dim3(mtiles, 2), 256, 0, stream>>>(att, Waot, bao, ffnb, aln_g, aln_b, out, NN);
}

// Round 3
// 451.857 us; speedup vs baseline: 1.0543x; 1.0543x over previous
//
#include <hip/hip_runtime.h>
#include <math.h>

#define NN 50000
#define EE 800000
#define AIN 256
#define OH 128

#define NTOT  (2 * NN)        // combined node ids: set0 = [0,NN), set1 = [NN,2NN)
#define NB    391             // buckets of 256 nodes
#define CAP   5120            // per-bucket stage capacity (mean 4092, +16 sigma)

typedef __attribute__((ext_vector_type(8))) short bf16x8;
typedef __attribute__((ext_vector_type(4))) float f32x4;
typedef __attribute__((ext_vector_type(2))) float f32x2;

static __device__ __forceinline__ unsigned short f2bf(float f) {
    union { float f; unsigned int u; } v; v.f = f;
    return (unsigned short)((v.u + 0x7FFFu + ((v.u >> 16) & 1u)) >> 16);
}
static __device__ __forceinline__ float bflo(unsigned int u) { return __uint_as_float(u << 16); }
static __device__ __forceinline__ float bfhi(unsigned int u) { return __uint_as_float(u & 0xFFFF0000u); }

// ---------------------------------------------------------------------------
__global__ __launch_bounds__(256) void cvt_x_k(const float* __restrict__ x, unsigned short* __restrict__ xb)
{
    const int i = blockIdx.x * 256 + threadIdx.x;
    if (i >= NN * AIN / 4) return;
    const float4 v = ((const float4*)x)[i];
    ushort4 o;
    o.x = f2bf(v.x); o.y = f2bf(v.y); o.z = f2bf(v.z); o.w = f2bf(v.w);
    ((ushort4*)xb)[i] = o;
}

__global__ __launch_bounds__(256) void cvt_w_k(
    const float* __restrict__ Wq, const float* __restrict__ Wk,
    const float* __restrict__ Wv, const float* __restrict__ Wf,
    const float* __restrict__ Wo, unsigned short* __restrict__ Wt,
    unsigned short* __restrict__ Waot)
{
    const int n = blockIdx.x;
    const int k = threadIdx.x;
    if (n < 512) {
        const float* W = (n < 128) ? Wq : (n < 256) ? Wk : (n < 384) ? Wv : Wf;
        Wt[(size_t)n * 256 + k] = f2bf(W[(size_t)k * OH + (n & 127)]);
    } else {
        if (k < 128) Waot[(size_t)(n - 512) * 128 + k] = f2bf(Wo[(size_t)k * OH + (n - 512)]);
    }
}

// ---------------------------------------------------------------------------
// Fused QKV+FFN GEMM, bf16 MFMA 16x16x32. 128x128 tile, BK=32, 4 waves.
// y=0 -> q (fp32 out), y=1 -> k (fp8 e4m3 into k8, stride 128B),
// y=2 -> v (bf16 into vb, stride 128), y=3 -> ffn (bf16).
// ---------------------------------------------------------------------------
__global__ __launch_bounds__(256) void qkvf_mfma_k(
    const unsigned short* __restrict__ xb,
    const unsigned short* __restrict__ Wt,
    const float* __restrict__ bq, const float* __restrict__ bk,
    const float* __restrict__ bv, const float* __restrict__ bf,
    float* __restrict__ qf, unsigned char* __restrict__ k8,
    unsigned short* __restrict__ vb,
    unsigned short* __restrict__ ffnb, int M)
{
    __shared__ unsigned short As[128][40];
    __shared__ unsigned short Bs[128][40];
    const int tid  = threadIdx.x;
    const int lane = tid & 63;
    const int wave = tid >> 6;
    const int wr = wave >> 1, wc = wave & 1;
    const int quad = lane >> 4, m16 = lane & 15;
    const int row0 = blockIdx.x * 128;
    const int col0 = blockIdx.y * 128;

    f32x4 acc[4][4];
    #pragma unroll
    for (int i = 0; i < 4; ++i)
        #pragma unroll
        for (int j = 0; j < 4; ++j) acc[i][j] = 0.f;

    const int lr  = tid >> 1;
    const int lkh = (tid & 1) * 16;

    for (int kt = 0; kt < 256; kt += 32) {
        uint4 a0 = {0,0,0,0}, a1 = {0,0,0,0};
        const int grow = row0 + lr;
        if (grow < M) {
            const uint4* p = (const uint4*)(xb + (size_t)grow * 256 + kt + lkh);
            a0 = p[0]; a1 = p[1];
        }
        *(uint4*)&As[lr][lkh]     = a0;
        *(uint4*)&As[lr][lkh + 8] = a1;
        const uint4* wp = (const uint4*)(Wt + (size_t)(col0 + lr) * 256 + kt + lkh);
        *(uint4*)&Bs[lr][lkh]     = wp[0];
        *(uint4*)&Bs[lr][lkh + 8] = wp[1];
        __syncthreads();
        bf16x8 af[4], bfr[4];
        #pragma unroll
        for (int t = 0; t < 4; ++t) af[t]  = *(const bf16x8*)&As[wr * 64 + t * 16 + m16][quad * 8];
        #pragma unroll
        for (int t = 0; t < 4; ++t) bfr[t] = *(const bf16x8*)&Bs[wc * 64 + t * 16 + m16][quad * 8];
        #pragma unroll
        for (int i = 0; i < 4; ++i)
            #pragma unroll
            for (int j = 0; j < 4; ++j)
                acc[i][j] = __builtin_amdgcn_mfma_f32_16x16x32_bf16(af[i], bfr[j], acc[i][j], 0, 0, 0);
        __syncthreads();
    }

    const int y = blockIdx.y;
    const float* bias = (y == 0) ? bq : (y == 1) ? bk : (y == 2) ? bv : bf;

    if (y == 0) {
        #pragma unroll
        for (int i = 0; i < 4; ++i)
            #pragma unroll
            for (int j = 0; j < 4; ++j) {
                const int col = wc * 64 + j * 16 + m16;
                const float b = bias[col];
                #pragma unroll
                for (int r = 0; r < 4; ++r) {
                    const int row = row0 + wr * 64 + i * 16 + quad * 4 + r;
                    if (row < M) qf[(size_t)row * 128 + col] = acc[i][j][r] + b;
                }
            }
    } else if (y == 1) {
        // k in fp8 e4m3 (OCP): HW pack, single-byte stores (6.4 MB total)
        #pragma unroll
        for (int i = 0; i < 4; ++i)
            #pragma unroll
            for (int j = 0; j < 4; ++j) {
                const int col = wc * 64 + j * 16 + m16;
                const float b = bias[col];
                #pragma unroll
                for (int r = 0; r < 4; ++r) {
                    const int row = row0 + wr * 64 + i * 16 + quad * 4 + r;
                    if (row < M) {
                        const unsigned int pk =
                            (unsigned int)__builtin_amdgcn_cvt_pk_fp8_f32(acc[i][j][r] + b, 0.f, 0, 0);
                        k8[(size_t)row * 128 + col] = (unsigned char)(pk & 0xFF);
                    }
                }
            }
    } else {
        unsigned short* obase = (y == 3) ? ffnb : vb;
        #pragma unroll
        for (int i = 0; i < 4; ++i)
            #pragma unroll
            for (int j = 0; j < 4; ++j) {
                const int col = wc * 64 + j * 16 + m16;
                const float b = bias[col];
                #pragma unroll
                for (int r = 0; r < 4; ++r) {
                    const int row = row0 + wr * 64 + i * 16 + quad * 4 + r;
                    if (row < M) obase[(size_t)row * 128 + col] = f2bf(acc[i][j][r] + b);
                }
            }
    }
}

// ---------------------------------------------------------------------------
// Pass 1: bin edges into NB buckets of 256 nodes. Stage record:
// x = f32 feat bits, y = (src << 8) | (nid & 255).
// ---------------------------------------------------------------------------
__global__ __launch_bounds__(256) void binpass_k(
    const int* __restrict__ dst0, const int* __restrict__ dst1,
    const int* __restrict__ src0, const int* __restrict__ src1,
    const float* __restrict__ feat0, const float* __restrict__ feat1,
    int* __restrict__ cursor, uint2* __restrict__ stage)
{
    __shared__ int hcnt[NB], blkbase[NB], lcur[NB];
    const int tid = threadIdx.x;
    const long base = (long)blockIdx.x * 8192;

    for (int i = tid; i < NB; i += 256) { hcnt[i] = 0; lcur[i] = 0; }
    __syncthreads();

    for (int i = tid; i < 8192; i += 256) {
        const long e = base + i;
        if (e < 2L * EE) {
            const int nid = (e < EE) ? dst0[e] : NN + dst1[e - EE];
            atomicAdd(&hcnt[nid >> 8], 1);
        }
    }
    __syncthreads();
    for (int i = tid; i < NB; i += 256)
        if (hcnt[i]) blkbase[i] = atomicAdd(&cursor[i], hcnt[i]);
    __syncthreads();

    for (int i = tid; i < 8192; i += 256) {
        const long e = base + i;
        if (e < 2L * EE) {
            const bool a = (e < EE);
            const int ee = a ? (int)e : (int)(e - EE);
            const int nid = a ? dst0[ee] : NN + dst1[ee];
            const int s = a ? src0[ee] : src1[ee];
            const float f = a ? feat0[(size_t)ee * 2] : feat1[(size_t)ee * 2];
            const int bk = nid >> 8;
            const int r = atomicAdd(&lcur[bk], 1);
            uint2 rec;
            rec.x = __float_as_uint(f);
            rec.y = ((unsigned int)s << 8) | (unsigned int)(nid & 255);
            stage[(size_t)bk * CAP + blkbase[bk] + r] = rec;
        }
    }
}

__global__ __launch_bounds__(512) void bscan_k(const int* __restrict__ cursor, int* __restrict__ bbase)
{
    __shared__ int part[512];
    const int t = threadIdx.x;
    const int v = (t < NB) ? cursor[t] : 0;
    part[t] = v;
    __syncthreads();
    for (int st = 1; st < 512; st <<= 1) {
        int u = (t >= st) ? part[t - st] : 0;
        __syncthreads();
        part[t] += u;
        __syncthreads();
    }
    if (t < NB) bbase[t] = part[t] - v;
}

// ---------------------------------------------------------------------------
// Pass 2: one block per bucket. Sort bucket records into node order; emit
// erec = {src, f32 feat} plus off/deg per node.
// ---------------------------------------------------------------------------
__global__ __launch_bounds__(256) void sortpass_k(
    const uint2* __restrict__ stage, const int* __restrict__ cursor,
    const int* __restrict__ bbase, uint2* __restrict__ erec,
    int* __restrict__ off, int* __restrict__ deg)
{
    __shared__ int h[256], eb[256], cur[256];
    const int b = blockIdx.x;
    const int t = threadIdx.x;
    const int cntb = cursor[b];
    const int obase = bbase[b];
    const uint2* sb = stage + (size_t)b * CAP;

    h[t] = 0; cur[t] = 0;
    __syncthreads();
    for (int i = t; i < cntb; i += 256) atomicAdd(&h[(int)(sb[i].y & 255u)], 1);
    __syncthreads();
    eb[t] = h[t];
    __syncthreads();
    for (int st = 1; st < 256; st <<= 1) {
        int u = (t >= st) ? eb[t - st] : 0;
        __syncthreads();
        eb[t] += u;
        __syncthreads();
    }
    const int incl = eb[t];
    __syncthreads();
    eb[t] = incl - h[t];          // exclusive
    __syncthreads();

    const int nid = b * 256 + t;
    if (nid < NTOT) {
        off[nid] = obase + eb[t];
        deg[nid] = h[t];
    }

    for (int i = t; i < cntb; i += 256) {
        const uint2 r = sb[i];
        const int loc = (int)(r.y & 255u);
        const int rk = atomicAdd(&cur[loc], 1);
        uint2 o;
        o.x = r.y >> 8;    // src
        o.y = r.x;         // f32 feat bits
        erec[obase + eb[loc] + rk] = o;
    }
}

// ---------------------------------------------------------------------------
// Aggregation, both edge sets in one dispatch: one wave per combined node id.
// Lane layout: g = lane>>4 is the edge slot (4 edges in flight per wave),
// d16 = lane&15 owns dims [d16*8, d16*8+8). k gathered as fp8 e4m3 (8B/lane,
// 128B/row — halves the K gather traffic vs bf16 and the 6.4 MB k8 table
// L2-caches far better than 12.8 MB); v gathered bf16 (16B/lane, 256B/row).
// HW pair-decode (v_cvt_pk_f32_fp8) keeps VALU ops/edge unchanged vs the
// bf16 bit-unpacks. Head reduce = 2 shfl_xor; score stays lane-resident for
// the V accumulation; cross-slot combine in the epilogue. q fp32.
// ---------------------------------------------------------------------------
__global__ __launch_bounds__(256) void aggregate_k(
    const float* __restrict__ qf, const unsigned char* __restrict__ k8,
    const unsigned short* __restrict__ vb, const uint2* __restrict__ erec,
    const int* __restrict__ off, const int* __restrict__ deg,
    unsigned short* __restrict__ att)
{
    const int nid = blockIdx.x * 4 + (threadIdx.x >> 6);
    if (nid >= NTOT) return;
    const int n = (nid >= NN) ? nid - NN : nid;
    const int lane = threadIdx.x & 63;
    const int g   = lane >> 4;     // edge slot 0..3
    const int d16 = lane & 15;     // dim-block: dims [d16*8, d16*8+8)
    const int start = off[nid];
    const int count = deg[nid];

    const float4* qp = (const float4*)(qf + (size_t)n * 128 + d16 * 8);
    const float4 qa = qp[0];
    const float4 qb = qp[1];

    float a0 = 0.f, a1 = 0.f, a2 = 0.f, a3 = 0.f;
    float a4 = 0.f, a5 = 0.f, a6 = 0.f, a7 = 0.f;
    float zp = 0.f;
    const float SCALE = 0.088388347648318447f;  // 1/sqrt(128)
    const unsigned char*  k8l = k8 + d16 * 8;   // lane-fixed dim offset
    const unsigned short* vbl = vb + d16 * 8;

    for (int base = 0; base < count; base += 64) {
        const int m = min(64, count - base);
        const uint2 rr = erec[start + base + min(lane, m - 1)];
        // prefetch batch 0 (dead slots read the clamped record: valid addr)
        int src = __shfl((int)rr.x, g);
        uint2 kc = *(const uint2*)(k8l + (size_t)src * 128);
        uint4 vc = *(const uint4*)(vbl + (size_t)src * 128);
        for (int j0 = 0; j0 < m; j0 += 4) {
            const uint2 kk = kc;
            const uint4 vv = vc;
            const float f = __int_as_float(__shfl((int)rr.y, j0 + g));
            const int jn = j0 + 4;
            if (jn < m) {      // uniform branch: prefetch next batch
                src = __shfl((int)rr.x, jn + g);
                kc = *(const uint2*)(k8l + (size_t)src * 128);
                vc = *(const uint4*)(vbl + (size_t)src * 128);
            }
            // decode 8 fp8 k dims (4 HW pair-converts), dot with fp32 q
            const f32x2 k01 = __builtin_amdgcn_cvt_pk_f32_fp8((int)kk.x, false);
            const f32x2 k23 = __builtin_amdgcn_cvt_pk_f32_fp8((int)kk.x, true);
            const f32x2 k45 = __builtin_amdgcn_cvt_pk_f32_fp8((int)kk.y, false);
            const f32x2 k67 = __builtin_amdgcn_cvt_pk_f32_fp8((int)kk.y, true);
            float p =        k01[0] * qa.x;
            p = fmaf(k01[1], qa.y, p);
            p = fmaf(k23[0], qa.z, p);
            p = fmaf(k23[1], qa.w, p);
            p = fmaf(k45[0], qb.x, p);
            p = fmaf(k45[1], qb.y, p);
            p = fmaf(k67[0], qb.z, p);
            p = fmaf(k67[1], qb.w, p);
            // head reduce: 4 lanes (d16 within the same head) = 32 dims
            p += __shfl_xor(p, 1);
            p += __shfl_xor(p, 2);
            float sc = __expf(fminf(5.f, fmaxf(-5.f, p * f * SCALE)));
            sc = (j0 + g < m) ? sc : 0.f;
            zp += sc;          // per-lane: my head's z over my slot's edges
            a0 = fmaf(bflo(vv.x), sc, a0);
            a1 = fmaf(bfhi(vv.x), sc, a1);
            a2 = fmaf(bflo(vv.y), sc, a2);
            a3 = fmaf(bfhi(vv.y), sc, a3);
            a4 = fmaf(bflo(vv.z), sc, a4);
            a5 = fmaf(bfhi(vv.z), sc, a5);
            a6 = fmaf(bflo(vv.w), sc, a6);
            a7 = fmaf(bfhi(vv.w), sc, a7);
        }
    }

    // combine the 4 edge slots (lane bits 4,5)
    float z = zp;
    z += __shfl_xor(z, 16);
    z += __shfl_xor(z, 32);
    a0 += __shfl_xor(a0, 16); a0 += __shfl_xor(a0, 32);
    a1 += __shfl_xor(a1, 16); a1 += __shfl_xor(a1, 32);
    a2 += __shfl_xor(a2, 16); a2 += __shfl_xor(a2, 32);
    a3 += __shfl_xor(a3, 16); a3 += __shfl_xor(a3, 32);
    a4 += __shfl_xor(a4, 16); a4 += __shfl_xor(a4, 32);
    a5 += __shfl_xor(a5, 16); a5 += __shfl_xor(a5, 32);
    a6 += __shfl_xor(a6, 16); a6 += __shfl_xor(a6, 32);
    a7 += __shfl_xor(a7, 16); a7 += __shfl_xor(a7, 32);

    const float inv = 1.f / (z + 1.f);   // per-head z (head = d16>>2)
    // slot g writes dims d16*8 + 2g, 2g+1 (static-index selects, no scratch)
    const float e0 = (g & 1) ? a2 : a0;
    const float e1 = (g & 1) ? a3 : a1;
    const float e2 = (g & 1) ? a6 : a4;
    const float e3 = (g & 1) ? a7 : a5;
    const float ax = ((g & 2) ? e2 : e0) * inv;
    const float ay = ((g & 2) ? e3 : e1) * inv;
    const unsigned int o = ((unsigned int)f2bf(ay) << 16) | (unsigned int)f2bf(ax);
    *(unsigned int*)(att + (size_t)nid * 128 + d16 * 8 + g * 2) = o;
}

// ---------------------------------------------------------------------------
// Output GEMM for both sets (blockIdx.y). LN epilogue fully in fp32 registers.
// ---------------------------------------------------------------------------
__global__ __launch_bounds__(256) void attn_out_mfma_k(
    const unsigned short* __restrict__ attAll, const unsigned short* __restrict__ Wt,
    const float* __restrict__ bo, const unsigned short* __restrict__ ffnb,
    const float* __restrict__ g, const float* __restrict__ bln,
    float* __restrict__ Yall, int M)
{
    __shared__ unsigned short As[128][40];
    __shared__ unsigned short Bs[128][40];
    __shared__ float rsum[2][128], rsq[2][128];
    __shared__ float meanar[128], invar[128];

    const unsigned short* att = attAll + (size_t)blockIdx.y * NN * 128;
    float* Y = Yall + (size_t)blockIdx.y * NN * 128;

    const int tid  = threadIdx.x;
    const int lane = tid & 63;
    const int wave = tid >> 6;
    const int wr = wave >> 1, wc = wave & 1;
    const int quad = lane >> 4, m16 = lane & 15;
    const int row0 = blockIdx.x * 128;

    f32x4 acc[4][4];
    #pragma unroll
    for (int i = 0; i < 4; ++i)
        #pragma unroll
        for (int j = 0; j < 4; ++j) acc[i][j] = 0.f;

    const int lr  = tid >> 1;
    const int lkh = (tid & 1) * 16;

    for (int kt = 0; kt < 128; kt += 32) {
        uint4 a0 = {0,0,0,0}, a1 = {0,0,0,0};
        const int grow = row0 + lr;
        if (grow < M) {
            const uint4* p = (const uint4*)(att + (size_t)grow * 128 + kt + lkh);
            a0 = p[0]; a1 = p[1];
        }
        *(uint4*)&As[lr][lkh]     = a0;
        *(uint4*)&As[lr][lkh + 8] = a1;
        const uint4* wp = (const uint4*)(Wt + (size_t)lr * 128 + kt + lkh);
        *(uint4*)&Bs[lr][lkh]     = wp[0];
        *(uint4*)&Bs[lr][lkh + 8] = wp[1];
        __syncthreads();
        bf16x8 af[4], bfr[4];
        #pragma unroll
        for (int t = 0; t < 4; ++t) af[t]  = *(const bf16x8*)&As[wr * 64 + t * 16 + m16][quad * 8];
        #pragma unroll
        for (int t = 0; t < 4; ++t) bfr[t] = *(const bf16x8*)&Bs[wc * 64 + t * 16 + m16][quad * 8];
        #pragma unroll
        for (int i = 0; i < 4; ++i)
            #pragma unroll
            for (int j = 0; j < 4; ++j)
                acc[i][j] = __builtin_amdgcn_mfma_f32_16x16x32_bf16(af[i], bfr[j], acc[i][j], 0, 0, 0);
        __syncthreads();
    }

    // ah = C + bo + ffn (fp32 in regs); per-row partial sums
    #pragma unroll
    for (int i = 0; i < 4; ++i) {
        #pragma unroll
        for (int r = 0; r < 4; ++r) {
            const int rl = wr * 64 + i * 16 + quad * 4 + r;
            const int grow = row0 + rl;
            float s = 0.f, q = 0.f;
            #pragma unroll
            for (int j = 0; j < 4; ++j) {
                const int col = wc * 64 + j * 16 + m16;
                float v = acc[i][j][r] + bo[col];
                if (grow < M) v += bflo(ffnb[(size_t)grow * 128 + col]);
                acc[i][j][r] = v;
                s += v; q += v * v;
            }
            #pragma unroll
            for (int mm = 1; mm <= 8; mm <<= 1) {
                s += __shfl_xor(s, mm, 16);
                q += __shfl_xor(q, mm, 16);
            }
            if (m16 == 0) { rsum[wc][rl] = s; rsq[wc][rl] = q; }
        }
    }
    __syncthreads();
    if (tid < 128) {
        const float s = rsum[0][tid] + rsum[1][tid];
        const float q = rsq[0][tid] + rsq[1][tid];
        const float mean = s * (1.f / 128.f);
        const float var  = q * (1.f / 128.f) - mean * mean;
        meanar[tid] = mean;
        invar[tid]  = rsqrtf(fmaxf(var, 0.f) + 1e-5f);
    }
    __syncthreads();

    #pragma unroll
    for (int i = 0; i < 4; ++i) {
        #pragma unroll
        for (int j = 0; j < 4; ++j) {
            const int col = wc * 64 + j * 16 + m16;
            const float gv = g[col], lv = bln[col];
            #pragma unroll
            for (int r = 0; r < 4; ++r) {
                const int rl = wr * 64 + i * 16 + quad * 4 + r;
                const int grow = row0 + rl;
                if (grow < M) {
                    const float v = acc[i][j][r];
                    Y[(size_t)grow * 128 + col] = v + (v - meanar[rl]) * invar[rl] * gv + lv;
                }
            }
        }
    }
}

// ---------------------------------------------------------------------------
extern "C" void kernel_launch(void* const* d_in, const int* in_sizes, int n_in,
                              void* d_out, int out_size, void* d_ws, size_t ws_size,
                              hipStream_t stream) {
    const float* x99   = (const float*)d_in[2];
    const float* feat0 = (const float*)d_in[3];
    const float* feat1 = (const float*)d_in[4];
    const float* Waq   = (const float*)d_in[10];
    const float* Wak   = (const float*)d_in[11];
    const float* Wav   = (const float*)d_in[12];
    const float* Wao   = (const float*)d_in[13];
    const float* Waffn = (const float*)d_in[14];
    const float* baq   = (const float*)d_in[20];
    const float* bak   = (const float*)d_in[21];
    const float* bav   = (const float*)d_in[22];
    const float* bao   = (const float*)d_in[23];
    const float* baffn = (const float*)d_in[24];
    const float* aln_b = (const float*)d_in[26];
    const float* aln_g = (const float*)d_in[28];
    const int* src0 = (const int*)d_in[29];
    const int* dst0 = (const int*)d_in[30];
    const int* src1 = (const int*)d_in[31];
    const int* dst1 = (const int*)d_in[32];

    // workspace (~110 MB)
    unsigned short* xb   = (unsigned short*)d_ws;                 // NN*256 us
    float*          qf   = (float*)(xb + (size_t)NN * 256);       // NN*128 f32
    unsigned short* vb   = (unsigned short*)(qf + (size_t)NN * 128);  // NN*128 us
    unsigned char*  k8   = (unsigned char*)(vb + (size_t)NN * 128);   // NN*128 bytes
    unsigned short* ffnb = (unsigned short*)(k8 + (size_t)NN * 128);  // NN*128 us
    unsigned short* att  = ffnb + (size_t)NN * 128;               // 2*NN*128 us
    unsigned short* Wt   = att  + (size_t)NTOT * 128;             // 512*256 us
    unsigned short* Waot = Wt   + (size_t)512 * 256;              // 128*128 us
    int* cursor = (int*)(Waot + 128 * 128);                       // NB
    int* bbase  = cursor + NB;                                    // NB
    int* off    = bbase + NB;                                     // NTOT
    int* deg    = off + NTOT;                                     // NTOT

    float* out = (float*)d_out;
    // stage (16.0 MB) + erec (12.8 MB) parked in d_out; both are fully
    // consumed (sortpass, aggregate) before attn_out writes d_out.
    uint2* stage = (uint2*)d_out;                                 // NB*CAP
    uint2* erec  = stage + (size_t)NB * CAP;                      // 2*EE

    cvt_x_k<<<(NN * AIN / 4 + 255) / 256, 256, 0, stream>>>(x99, xb);
    cvt_w_k<<<640, 256, 0, stream>>>(Waq, Wak, Wav, Waffn, Wao, Wt, Waot);

    const int mtiles = (NN + 127) / 128;   // 391
    qkvf_mfma_k<<<dim3(mtiles, 4), 256, 0, stream>>>(xb, Wt, baq, bak, bav, baffn, qf, k8, vb, ffnb, NN);

    hipMemsetAsync(cursor, 0, NB * sizeof(int), stream);
    binpass_k<<<(2 * EE + 8191) / 8192, 256, 0, stream>>>(
        dst0, dst1, src0, src1, feat0, feat1, cursor, stage);
    bscan_k<<<1, 512, 0, stream>>>(cursor, bbase);
    sortpass_k<<<NB, 256, 0, stream>>>(stage, cursor, bbase, erec, off, deg);

    aggregate_k<<<(NTOT + 3) / 4, 256, 0, stream>>>(qf, k8, vb, erec, off, deg, att);
    attn_out_mfma_k<<<dim3(mtiles, 2), 256, 0, stream>>>(att, Waot, bao, ffnb, aln_g, aln_b, out, NN);
}

// Round 4
// 432.837 us; speedup vs baseline: 1.1006x; 1.0439x over previous
//
#include <hip/hip_runtime.h>
#include <math.h>

#define NN 50000
#define EE 800000
#define AIN 256
#define OH 128

#define NTOT  (2 * NN)        // combined node ids: set0 = [0,NN), set1 = [NN,2NN)
#define NB    391             // buckets of 256 nodes
#define CAP   5120            // per-bucket stage capacity (mean 4092, +16 sigma)

typedef __attribute__((ext_vector_type(8))) short bf16x8;
typedef __attribute__((ext_vector_type(4))) float f32x4;
typedef __attribute__((ext_vector_type(2))) float f32x2;

static __device__ __forceinline__ unsigned short f2bf(float f) {
    union { float f; unsigned int u; } v; v.f = f;
    return (unsigned short)((v.u + 0x7FFFu + ((v.u >> 16) & 1u)) >> 16);
}
static __device__ __forceinline__ float bflo(unsigned int u) { return __uint_as_float(u << 16); }
static __device__ __forceinline__ float bfhi(unsigned int u) { return __uint_as_float(u & 0xFFFF0000u); }

// ---------------------------------------------------------------------------
__global__ __launch_bounds__(256) void cvt_x_k(const float* __restrict__ x, unsigned short* __restrict__ xb)
{
    const int i = blockIdx.x * 256 + threadIdx.x;
    if (i >= NN * AIN / 4) return;
    const float4 v = ((const float4*)x)[i];
    ushort4 o;
    o.x = f2bf(v.x); o.y = f2bf(v.y); o.z = f2bf(v.z); o.w = f2bf(v.w);
    ((ushort4*)xb)[i] = o;
}

__global__ __launch_bounds__(256) void cvt_w_k(
    const float* __restrict__ Wq, const float* __restrict__ Wk,
    const float* __restrict__ Wv, const float* __restrict__ Wf,
    const float* __restrict__ Wo, unsigned short* __restrict__ Wt,
    unsigned short* __restrict__ Waot)
{
    const int n = blockIdx.x;
    const int k = threadIdx.x;
    if (n < 512) {
        const float* W = (n < 128) ? Wq : (n < 256) ? Wk : (n < 384) ? Wv : Wf;
        Wt[(size_t)n * 256 + k] = f2bf(W[(size_t)k * OH + (n & 127)]);
    } else {
        if (k < 128) Waot[(size_t)(n - 512) * 128 + k] = f2bf(Wo[(size_t)k * OH + (n - 512)]);
    }
}

// ---------------------------------------------------------------------------
// Fused QKV+FFN GEMM, bf16 MFMA 16x16x32. 128x128 tile, BK=32, 4 waves.
// y=0 -> q (bf16 into qb), y=1 -> k (fp8 e4m3 into kv8 row bytes [0,128)),
// y=2 -> v (fp8 e4m3 into kv8 row bytes [128,256)), y=3 -> ffn (bf16).
// ---------------------------------------------------------------------------
__global__ __launch_bounds__(256) void qkvf_mfma_k(
    const unsigned short* __restrict__ xb,
    const unsigned short* __restrict__ Wt,
    const float* __restrict__ bq, const float* __restrict__ bk,
    const float* __restrict__ bv, const float* __restrict__ bf,
    unsigned short* __restrict__ qb, unsigned char* __restrict__ kv8,
    unsigned short* __restrict__ ffnb, int M)
{
    __shared__ unsigned short As[128][40];
    __shared__ unsigned short Bs[128][40];
    const int tid  = threadIdx.x;
    const int lane = tid & 63;
    const int wave = tid >> 6;
    const int wr = wave >> 1, wc = wave & 1;
    const int quad = lane >> 4, m16 = lane & 15;
    const int row0 = blockIdx.x * 128;
    const int col0 = blockIdx.y * 128;

    f32x4 acc[4][4];
    #pragma unroll
    for (int i = 0; i < 4; ++i)
        #pragma unroll
        for (int j = 0; j < 4; ++j) acc[i][j] = 0.f;

    const int lr  = tid >> 1;
    const int lkh = (tid & 1) * 16;

    for (int kt = 0; kt < 256; kt += 32) {
        uint4 a0 = {0,0,0,0}, a1 = {0,0,0,0};
        const int grow = row0 + lr;
        if (grow < M) {
            const uint4* p = (const uint4*)(xb + (size_t)grow * 256 + kt + lkh);
            a0 = p[0]; a1 = p[1];
        }
        *(uint4*)&As[lr][lkh]     = a0;
        *(uint4*)&As[lr][lkh + 8] = a1;
        const uint4* wp = (const uint4*)(Wt + (size_t)(col0 + lr) * 256 + kt + lkh);
        *(uint4*)&Bs[lr][lkh]     = wp[0];
        *(uint4*)&Bs[lr][lkh + 8] = wp[1];
        __syncthreads();
        bf16x8 af[4], bfr[4];
        #pragma unroll
        for (int t = 0; t < 4; ++t) af[t]  = *(const bf16x8*)&As[wr * 64 + t * 16 + m16][quad * 8];
        #pragma unroll
        for (int t = 0; t < 4; ++t) bfr[t] = *(const bf16x8*)&Bs[wc * 64 + t * 16 + m16][quad * 8];
        #pragma unroll
        for (int i = 0; i < 4; ++i)
            #pragma unroll
            for (int j = 0; j < 4; ++j)
                acc[i][j] = __builtin_amdgcn_mfma_f32_16x16x32_bf16(af[i], bfr[j], acc[i][j], 0, 0, 0);
        __syncthreads();
    }

    const int y = blockIdx.y;
    const float* bias = (y == 0) ? bq : (y == 1) ? bk : (y == 2) ? bv : bf;

    if (y == 1 || y == 2) {
        // k/v in fp8 e4m3 (OCP): HW pack, single-byte stores into the
        // interleaved kv8 row ([0,128)=K, [128,256)=V)
        const int ocol = (y == 2) ? 128 : 0;
        #pragma unroll
        for (int i = 0; i < 4; ++i)
            #pragma unroll
            for (int j = 0; j < 4; ++j) {
                const int col = wc * 64 + j * 16 + m16;
                const float b = bias[col];
                #pragma unroll
                for (int r = 0; r < 4; ++r) {
                    const int row = row0 + wr * 64 + i * 16 + quad * 4 + r;
                    if (row < M) {
                        const unsigned int pk =
                            (unsigned int)__builtin_amdgcn_cvt_pk_fp8_f32(acc[i][j][r] + b, 0.f, 0, 0);
                        kv8[(size_t)row * 256 + ocol + col] = (unsigned char)(pk & 0xFF);
                    }
                }
            }
    } else {
        unsigned short* obase = (y == 3) ? ffnb : qb;
        #pragma unroll
        for (int i = 0; i < 4; ++i)
            #pragma unroll
            for (int j = 0; j < 4; ++j) {
                const int col = wc * 64 + j * 16 + m16;
                const float b = bias[col];
                #pragma unroll
                for (int r = 0; r < 4; ++r) {
                    const int row = row0 + wr * 64 + i * 16 + quad * 4 + r;
                    if (row < M) obase[(size_t)row * 128 + col] = f2bf(acc[i][j][r] + b);
                }
            }
    }
}

// ---------------------------------------------------------------------------
// Pass 1: bin edges into NB buckets of 256 nodes. Stage record:
// x = f32 feat bits, y = (src << 8) | (nid & 255).
// ---------------------------------------------------------------------------
__global__ __launch_bounds__(256) void binpass_k(
    const int* __restrict__ dst0, const int* __restrict__ dst1,
    const int* __restrict__ src0, const int* __restrict__ src1,
    const float* __restrict__ feat0, const float* __restrict__ feat1,
    int* __restrict__ cursor, uint2* __restrict__ stage)
{
    __shared__ int hcnt[NB], blkbase[NB], lcur[NB];
    const int tid = threadIdx.x;
    const long base = (long)blockIdx.x * 8192;

    for (int i = tid; i < NB; i += 256) { hcnt[i] = 0; lcur[i] = 0; }
    __syncthreads();

    for (int i = tid; i < 8192; i += 256) {
        const long e = base + i;
        if (e < 2L * EE) {
            const int nid = (e < EE) ? dst0[e] : NN + dst1[e - EE];
            atomicAdd(&hcnt[nid >> 8], 1);
        }
    }
    __syncthreads();
    for (int i = tid; i < NB; i += 256)
        if (hcnt[i]) blkbase[i] = atomicAdd(&cursor[i], hcnt[i]);
    __syncthreads();

    for (int i = tid; i < 8192; i += 256) {
        const long e = base + i;
        if (e < 2L * EE) {
            const bool a = (e < EE);
            const int ee = a ? (int)e : (int)(e - EE);
            const int nid = a ? dst0[ee] : NN + dst1[ee];
            const int s = a ? src0[ee] : src1[ee];
            const float f = a ? feat0[(size_t)ee * 2] : feat1[(size_t)ee * 2];
            const int bk = nid >> 8;
            const int r = atomicAdd(&lcur[bk], 1);
            uint2 rec;
            rec.x = __float_as_uint(f);
            rec.y = ((unsigned int)s << 8) | (unsigned int)(nid & 255);
            stage[(size_t)bk * CAP + blkbase[bk] + r] = rec;
        }
    }
}

__global__ __launch_bounds__(512) void bscan_k(const int* __restrict__ cursor, int* __restrict__ bbase)
{
    __shared__ int part[512];
    const int t = threadIdx.x;
    const int v = (t < NB) ? cursor[t] : 0;
    part[t] = v;
    __syncthreads();
    for (int st = 1; st < 512; st <<= 1) {
        int u = (t >= st) ? part[t - st] : 0;
        __syncthreads();
        part[t] += u;
        __syncthreads();
    }
    if (t < NB) bbase[t] = part[t] - v;
}

// ---------------------------------------------------------------------------
// Pass 2: one block per bucket. Sort bucket records into node order; emit
// erec = {src, f32 feat} plus off/deg per node.
// ---------------------------------------------------------------------------
__global__ __launch_bounds__(256) void sortpass_k(
    const uint2* __restrict__ stage, const int* __restrict__ cursor,
    const int* __restrict__ bbase, uint2* __restrict__ erec,
    int* __restrict__ off, int* __restrict__ deg)
{
    __shared__ int h[256], eb[256], cur[256];
    const int b = blockIdx.x;
    const int t = threadIdx.x;
    const int cntb = cursor[b];
    const int obase = bbase[b];
    const uint2* sb = stage + (size_t)b * CAP;

    h[t] = 0; cur[t] = 0;
    __syncthreads();
    for (int i = t; i < cntb; i += 256) atomicAdd(&h[(int)(sb[i].y & 255u)], 1);
    __syncthreads();
    eb[t] = h[t];
    __syncthreads();
    for (int st = 1; st < 256; st <<= 1) {
        int u = (t >= st) ? eb[t - st] : 0;
        __syncthreads();
        eb[t] += u;
        __syncthreads();
    }
    const int incl = eb[t];
    __syncthreads();
    eb[t] = incl - h[t];          // exclusive
    __syncthreads();

    const int nid = b * 256 + t;
    if (nid < NTOT) {
        off[nid] = obase + eb[t];
        deg[nid] = h[t];
    }

    for (int i = t; i < cntb; i += 256) {
        const uint2 r = sb[i];
        const int loc = (int)(r.y & 255u);
        const int rk = atomicAdd(&cur[loc], 1);
        uint2 o;
        o.x = r.y >> 8;    // src
        o.y = r.x;         // f32 feat bits
        erec[obase + eb[loc] + rk] = o;
    }
}

// ---------------------------------------------------------------------------
// Aggregation, both edge sets in one dispatch: one wave per combined node id.
// Lane layout: g = lane>>4 is the edge slot (4 edges in flight per wave),
// d16 = lane&15 owns dims [d16*8, d16*8+8). K and V both fp8 e4m3 in ONE
// interleaved 256B row ([0,128)=K, [128,256)=V): per edge one base address,
// two 8B loads (V at +128 imm). Gather request bytes: 256B/edge (was 384);
// kv8 table 12.8 MB total. q bf16 (256B/row). HW pair-decode
// (v_cvt_pk_f32_fp8) + f32x2 vector math (packed-fma friendly). Head reduce
// = 2 shfl_xor; score stays lane-resident for V accumulation; cross-slot
// combine in the epilogue.
// ---------------------------------------------------------------------------
__global__ __launch_bounds__(256) void aggregate_k(
    const unsigned short* __restrict__ qb, const unsigned char* __restrict__ kv8,
    const uint2* __restrict__ erec,
    const int* __restrict__ off, const int* __restrict__ deg,
    unsigned short* __restrict__ att)
{
    const int nid = blockIdx.x * 4 + (threadIdx.x >> 6);
    if (nid >= NTOT) return;
    const int n = (nid >= NN) ? nid - NN : nid;
    const int lane = threadIdx.x & 63;
    const int g   = lane >> 4;     // edge slot 0..3
    const int d16 = lane & 15;     // dim-block: dims [d16*8, d16*8+8)
    const int start = off[nid];
    const int count = deg[nid];

    // q: my 8 dims, bf16 -> f32x2 pairs (dims 2i, 2i+1)
    const uint4 qu = *(const uint4*)(qb + (size_t)n * 128 + d16 * 8);
    f32x2 qd0, qd1, qd2, qd3;
    qd0[0] = bflo(qu.x); qd0[1] = bfhi(qu.x);
    qd1[0] = bflo(qu.y); qd1[1] = bfhi(qu.y);
    qd2[0] = bflo(qu.z); qd2[1] = bfhi(qu.z);
    qd3[0] = bflo(qu.w); qd3[1] = bfhi(qu.w);

    f32x2 av0 = 0.f, av1 = 0.f, av2 = 0.f, av3 = 0.f;
    float zp = 0.f;
    const float SCALE = 0.088388347648318447f;  // 1/sqrt(128)
    const unsigned char* kvl = kv8 + d16 * 8;   // lane-fixed dim offset

    for (int base = 0; base < count; base += 64) {
        const int m = min(64, count - base);
        const uint2 rr = erec[start + base + min(lane, m - 1)];
        // prefetch batch 0 (dead slots read the clamped record: valid addr)
        int src = __shfl((int)rr.x, g);
        const unsigned char* rp = kvl + (size_t)src * 256;
        uint2 kc = *(const uint2*)rp;
        uint2 vc = *(const uint2*)(rp + 128);
        for (int j0 = 0; j0 < m; j0 += 4) {
            const uint2 kk = kc;
            const uint2 vv = vc;
            const float f = __int_as_float(__shfl((int)rr.y, j0 + g));
            const int jn = j0 + 4;
            if (jn < m) {      // uniform branch: prefetch next batch
                src = __shfl((int)rr.x, jn + g);
                const unsigned char* rn = kvl + (size_t)src * 256;
                kc = *(const uint2*)rn;
                vc = *(const uint2*)(rn + 128);
            }
            // decode 8 fp8 k dims (4 HW pair-converts), packed dot with q
            const f32x2 k0 = __builtin_amdgcn_cvt_pk_f32_fp8((int)kk.x, false);
            const f32x2 k1 = __builtin_amdgcn_cvt_pk_f32_fp8((int)kk.x, true);
            const f32x2 k2 = __builtin_amdgcn_cvt_pk_f32_fp8((int)kk.y, false);
            const f32x2 k3 = __builtin_amdgcn_cvt_pk_f32_fp8((int)kk.y, true);
            f32x2 p2 = k0 * qd0;
            p2 += k1 * qd1;
            p2 += k2 * qd2;
            p2 += k3 * qd3;
            float p = p2[0] + p2[1];
            // head reduce: 4 lanes (d16 within the same head) = 32 dims
            p += __shfl_xor(p, 1);
            p += __shfl_xor(p, 2);
            float sc = __expf(fminf(5.f, fmaxf(-5.f, p * f * SCALE)));
            sc = (j0 + g < m) ? sc : 0.f;
            zp += sc;          // per-lane: my head's z over my slot's edges
            // decode 8 fp8 v dims, packed weighted accumulate
            const f32x2 v0 = __builtin_amdgcn_cvt_pk_f32_fp8((int)vv.x, false);
            const f32x2 v1 = __builtin_amdgcn_cvt_pk_f32_fp8((int)vv.x, true);
            const f32x2 v2 = __builtin_amdgcn_cvt_pk_f32_fp8((int)vv.y, false);
            const f32x2 v3 = __builtin_amdgcn_cvt_pk_f32_fp8((int)vv.y, true);
            f32x2 sc2; sc2[0] = sc; sc2[1] = sc;
            av0 += v0 * sc2;
            av1 += v1 * sc2;
            av2 += v2 * sc2;
            av3 += v3 * sc2;
        }
    }

    // combine the 4 edge slots (lane bits 4,5)
    float z = zp;
    z += __shfl_xor(z, 16);
    z += __shfl_xor(z, 32);
    av0[0] += __shfl_xor(av0[0], 16); av0[0] += __shfl_xor(av0[0], 32);
    av0[1] += __shfl_xor(av0[1], 16); av0[1] += __shfl_xor(av0[1], 32);
    av1[0] += __shfl_xor(av1[0], 16); av1[0] += __shfl_xor(av1[0], 32);
    av1[1] += __shfl_xor(av1[1], 16); av1[1] += __shfl_xor(av1[1], 32);
    av2[0] += __shfl_xor(av2[0], 16); av2[0] += __shfl_xor(av2[0], 32);
    av2[1] += __shfl_xor(av2[1], 16); av2[1] += __shfl_xor(av2[1], 32);
    av3[0] += __shfl_xor(av3[0], 16); av3[0] += __shfl_xor(av3[0], 32);
    av3[1] += __shfl_xor(av3[1], 16); av3[1] += __shfl_xor(av3[1], 32);

    const float inv = 1.f / (z + 1.f);   // per-head z (head = d16>>2)
    // slot g writes dims d16*8 + 2g, 2g+1 = av<g> (static selects, no scratch)
    const f32x2 e01 = (g & 1) ? av1 : av0;
    const f32x2 e23 = (g & 1) ? av3 : av2;
    const f32x2 e   = (g & 2) ? e23 : e01;
    const float ax = e[0] * inv;
    const float ay = e[1] * inv;
    const unsigned int o = ((unsigned int)f2bf(ay) << 16) | (unsigned int)f2bf(ax);
    *(unsigned int*)(att + (size_t)nid * 128 + d16 * 8 + g * 2) = o;
}

// ---------------------------------------------------------------------------
// Output GEMM for both sets (blockIdx.y). LN epilogue fully in fp32 registers.
// ---------------------------------------------------------------------------
__global__ __launch_bounds__(256) void attn_out_mfma_k(
    const unsigned short* __restrict__ attAll, const unsigned short* __restrict__ Wt,
    const float* __restrict__ bo, const unsigned short* __restrict__ ffnb,
    const float* __restrict__ g, const float* __restrict__ bln,
    float* __restrict__ Yall, int M)
{
    __shared__ unsigned short As[128][40];
    __shared__ unsigned short Bs[128][40];
    __shared__ float rsum[2][128], rsq[2][128];
    __shared__ float meanar[128], invar[128];

    const unsigned short* att = attAll + (size_t)blockIdx.y * NN * 128;
    float* Y = Yall + (size_t)blockIdx.y * NN * 128;

    const int tid  = threadIdx.x;
    const int lane = tid & 63;
    const int wave = tid >> 6;
    const int wr = wave >> 1, wc = wave & 1;
    const int quad = lane >> 4, m16 = lane & 15;
    const int row0 = blockIdx.x * 128;

    f32x4 acc[4][4];
    #pragma unroll
    for (int i = 0; i < 4; ++i)
        #pragma unroll
        for (int j = 0; j < 4; ++j) acc[i][j] = 0.f;

    const int lr  = tid >> 1;
    const int lkh = (tid & 1) * 16;

    for (int kt = 0; kt < 128; kt += 32) {
        uint4 a0 = {0,0,0,0}, a1 = {0,0,0,0};
        const int grow = row0 + lr;
        if (grow < M) {
            const uint4* p = (const uint4*)(att + (size_t)grow * 128 + kt + lkh);
            a0 = p[0]; a1 = p[1];
        }
        *(uint4*)&As[lr][lkh]     = a0;
        *(uint4*)&As[lr][lkh + 8] = a1;
        const uint4* wp = (const uint4*)(Wt + (size_t)lr * 128 + kt + lkh);
        *(uint4*)&Bs[lr][lkh]     = wp[0];
        *(uint4*)&Bs[lr][lkh + 8] = wp[1];
        __syncthreads();
        bf16x8 af[4], bfr[4];
        #pragma unroll
        for (int t = 0; t < 4; ++t) af[t]  = *(const bf16x8*)&As[wr * 64 + t * 16 + m16][quad * 8];
        #pragma unroll
        for (int t = 0; t < 4; ++t) bfr[t] = *(const bf16x8*)&Bs[wc * 64 + t * 16 + m16][quad * 8];
        #pragma unroll
        for (int i = 0; i < 4; ++i)
            #pragma unroll
            for (int j = 0; j < 4; ++j)
                acc[i][j] = __builtin_amdgcn_mfma_f32_16x16x32_bf16(af[i], bfr[j], acc[i][j], 0, 0, 0);
        __syncthreads();
    }

    // ah = C + bo + ffn (fp32 in regs); per-row partial sums
    #pragma unroll
    for (int i = 0; i < 4; ++i) {
        #pragma unroll
        for (int r = 0; r < 4; ++r) {
            const int rl = wr * 64 + i * 16 + quad * 4 + r;
            const int grow = row0 + rl;
            float s = 0.f, q = 0.f;
            #pragma unroll
            for (int j = 0; j < 4; ++j) {
                const int col = wc * 64 + j * 16 + m16;
                float v = acc[i][j][r] + bo[col];
                if (grow < M) v += bflo(ffnb[(size_t)grow * 128 + col]);
                acc[i][j][r] = v;
                s += v; q += v * v;
            }
            #pragma unroll
            for (int mm = 1; mm <= 8; mm <<= 1) {
                s += __shfl_xor(s, mm, 16);
                q += __shfl_xor(q, mm, 16);
            }
            if (m16 == 0) { rsum[wc][rl] = s; rsq[wc][rl] = q; }
        }
    }
    __syncthreads();
    if (tid < 128) {
        const float s = rsum[0][tid] + rsum[1][tid];
        const float q = rsq[0][tid] + rsq[1][tid];
        const float mean = s * (1.f / 128.f);
        const float var  = q * (1.f / 128.f) - mean * mean;
        meanar[tid] = mean;
        invar[tid]  = rsqrtf(fmaxf(var, 0.f) + 1e-5f);
    }
    __syncthreads();

    #pragma unroll
    for (int i = 0; i < 4; ++i) {
        #pragma unroll
        for (int j = 0; j < 4; ++j) {
            const int col = wc * 64 + j * 16 + m16;
            const float gv = g[col], lv = bln[col];
            #pragma unroll
            for (int r = 0; r < 4; ++r) {
                const int rl = wr * 64 + i * 16 + quad * 4 + r;
                const int grow = row0 + rl;
                if (grow < M) {
                    const float v = acc[i][j][r];
                    Y[(size_t)grow * 128 + col] = v + (v - meanar[rl]) * invar[rl] * gv + lv;
                }
            }
        }
    }
}

// ---------------------------------------------------------------------------
extern "C" void kernel_launch(void* const* d_in, const int* in_sizes, int n_in,
                              void* d_out, int out_size, void* d_ws, size_t ws_size,
                              hipStream_t stream) {
    const float* x99   = (const float*)d_in[2];
    const float* feat0 = (const float*)d_in[3];
    const float* feat1 = (const float*)d_in[4];
    const float* Waq   = (const float*)d_in[10];
    const float* Wak   = (const float*)d_in[11];
    const float* Wav   = (const float*)d_in[12];
    const float* Wao   = (const float*)d_in[13];
    const float* Waffn = (const float*)d_in[14];
    const float* baq   = (const float*)d_in[20];
    const float* bak   = (const float*)d_in[21];
    const float* bav   = (const float*)d_in[22];
    const float* bao   = (const float*)d_in[23];
    const float* baffn = (const float*)d_in[24];
    const float* aln_b = (const float*)d_in[26];
    const float* aln_g = (const float*)d_in[28];
    const int* src0 = (const int*)d_in[29];
    const int* dst0 = (const int*)d_in[30];
    const int* src1 = (const int*)d_in[31];
    const int* dst1 = (const int*)d_in[32];

    // workspace (~103 MB)
    unsigned short* xb   = (unsigned short*)d_ws;                 // NN*256 us
    unsigned short* qb   = xb + (size_t)NN * 256;                 // NN*128 us
    unsigned char*  kv8  = (unsigned char*)(qb + (size_t)NN * 128);   // NN*256 bytes
    unsigned short* ffnb = (unsigned short*)(kv8 + (size_t)NN * 256); // NN*128 us
    unsigned short* att  = ffnb + (size_t)NN * 128;               // 2*NN*128 us
    unsigned short* Wt   = att  + (size_t)NTOT * 128;             // 512*256 us
    unsigned short* Waot = Wt   + (size_t)512 * 256;              // 128*128 us
    int* cursor = (int*)(Waot + 128 * 128);                       // NB
    int* bbase  = cursor + NB;                                    // NB
    int* off    = bbase + NB;                                     // NTOT
    int* deg    = off + NTOT;                                     // NTOT

    float* out = (float*)d_out;
    // stage (16.0 MB) + erec (12.8 MB) parked in d_out; both are fully
    // consumed (sortpass, aggregate) before attn_out writes d_out.
    uint2* stage = (uint2*)d_out;                                 // NB*CAP
    uint2* erec  = stage + (size_t)NB * CAP;                      // 2*EE

    cvt_x_k<<<(NN * AIN / 4 + 255) / 256, 256, 0, stream>>>(x99, xb);
    cvt_w_k<<<640, 256, 0, stream>>>(Waq, Wak, Wav, Waffn, Wao, Wt, Waot);

    const int mtiles = (NN + 127) / 128;   // 391
    qkvf_mfma_k<<<dim3(mtiles, 4), 256, 0, stream>>>(xb, Wt, baq, bak, bav, baffn, qb, kv8, ffnb, NN);

    hipMemsetAsync(cursor, 0, NB * sizeof(int), stream);
    binpass_k<<<(2 * EE + 8191) / 8192, 256, 0, stream>>>(
        dst0, dst1, src0, src1, feat0, feat1, cursor, stage);
    bscan_k<<<1, 512, 0, stream>>>(cursor, bbase);
    sortpass_k<<<NB, 256, 0, stream>>>(stage, cursor, bbase, erec, off, deg);

    aggregate_k<<<(NTOT + 3) / 4, 256, 0, stream>>>(qb, kv8, erec, off, deg, att);
    attn_out_mfma_k<<<dim3(mtiles, 2), 256, 0, stream>>>(att, Waot, bao, ffnb, aln_g, aln_b, out, NN);
}

// Round 5
// 431.847 us; speedup vs baseline: 1.1032x; 1.0023x over previous
//
#include <hip/hip_runtime.h>
#include <math.h>

#define NN 50000
#define EE 800000
#define AIN 256
#define OH 128

#define NTOT  (2 * NN)        // combined node ids: set0 = [0,NN), set1 = [NN,2NN)
#define NB    391             // buckets of 256 nodes
#define CAP   5120            // per-bucket stage capacity (mean 4092, +16 sigma)
#define MT    391             // row tiles (128 rows each)
#define RPX   49              // ceil(MT/8) row tiles per XCD

typedef __attribute__((ext_vector_type(8))) short bf16x8;
typedef __attribute__((ext_vector_type(4))) float f32x4;
typedef __attribute__((ext_vector_type(2))) float f32x2;

static __device__ __forceinline__ unsigned short f2bf(float f) {
    union { float f; unsigned int u; } v; v.f = f;
    return (unsigned short)((v.u + 0x7FFFu + ((v.u >> 16) & 1u)) >> 16);
}
static __device__ __forceinline__ float bflo(unsigned int u) { return __uint_as_float(u << 16); }
static __device__ __forceinline__ float bfhi(unsigned int u) { return __uint_as_float(u & 0xFFFF0000u); }

// ---------------------------------------------------------------------------
__global__ __launch_bounds__(256) void cvt_x_k(const float* __restrict__ x, unsigned short* __restrict__ xb)
{
    const int i = blockIdx.x * 256 + threadIdx.x;
    if (i >= NN * AIN / 4) return;
    const float4 v = ((const float4*)x)[i];
    ushort4 o;
    o.x = f2bf(v.x); o.y = f2bf(v.y); o.z = f2bf(v.z); o.w = f2bf(v.w);
    ((ushort4*)xb)[i] = o;
}

__global__ __launch_bounds__(256) void cvt_w_k(
    const float* __restrict__ Wq, const float* __restrict__ Wk,
    const float* __restrict__ Wv, const float* __restrict__ Wf,
    const float* __restrict__ Wo, unsigned short* __restrict__ Wt,
    unsigned short* __restrict__ Waot)
{
    const int n = blockIdx.x;
    const int k = threadIdx.x;
    if (n < 512) {
        const float* W = (n < 128) ? Wq : (n < 256) ? Wk : (n < 384) ? Wv : Wf;
        Wt[(size_t)n * 256 + k] = f2bf(W[(size_t)k * OH + (n & 127)]);
    } else {
        if (k < 128) Waot[(size_t)(n - 512) * 128 + k] = f2bf(Wo[(size_t)k * OH + (n - 512)]);
    }
}

// ---------------------------------------------------------------------------
// Fused QKV+FFN GEMM, bf16 MFMA 16x16x32. 128x128 tile, BK=32, 4 waves.
// XCD-swizzled 1D grid (8 * RPX * 4 blocks): xcd = n&7 owns row tiles
// [xcd*RPX, xcd*RPX+RPX); the 4 y-tiles of one row tile are id-adjacent and
// land on the SAME XCD -> the A stripe (3.2 MB/XCD) L2-caches, cutting A
// fill 4x. y=0 -> q (bf16), y=1 -> k (fp8 into kv8 [0,128)), y=2 -> v (fp8
// into kv8 [128,256)), y=3 -> ffn (bf16).
// ---------------------------------------------------------------------------
__global__ __launch_bounds__(256) void qkvf_mfma_k(
    const unsigned short* __restrict__ xb,
    const unsigned short* __restrict__ Wt,
    const float* __restrict__ bq, const float* __restrict__ bk,
    const float* __restrict__ bv, const float* __restrict__ bf,
    unsigned short* __restrict__ qb, unsigned char* __restrict__ kv8,
    unsigned short* __restrict__ ffnb, int M)
{
    const int nblk = blockIdx.x;
    const int xcd  = nblk & 7;
    const int slot = nblk >> 3;
    const int rowt = xcd * RPX + (slot >> 2);
    const int y    = slot & 3;
    if (rowt >= MT) return;

    __shared__ unsigned short As[128][40];
    __shared__ unsigned short Bs[128][40];
    const int tid  = threadIdx.x;
    const int lane = tid & 63;
    const int wave = tid >> 6;
    const int wr = wave >> 1, wc = wave & 1;
    const int quad = lane >> 4, m16 = lane & 15;
    const int row0 = rowt * 128;
    const int col0 = y * 128;

    f32x4 acc[4][4];
    #pragma unroll
    for (int i = 0; i < 4; ++i)
        #pragma unroll
        for (int j = 0; j < 4; ++j) acc[i][j] = 0.f;

    const int lr  = tid >> 1;
    const int lkh = (tid & 1) * 16;

    for (int kt = 0; kt < 256; kt += 32) {
        uint4 a0 = {0,0,0,0}, a1 = {0,0,0,0};
        const int grow = row0 + lr;
        if (grow < M) {
            const uint4* p = (const uint4*)(xb + (size_t)grow * 256 + kt + lkh);
            a0 = p[0]; a1 = p[1];
        }
        *(uint4*)&As[lr][lkh]     = a0;
        *(uint4*)&As[lr][lkh + 8] = a1;
        const uint4* wp = (const uint4*)(Wt + (size_t)(col0 + lr) * 256 + kt + lkh);
        *(uint4*)&Bs[lr][lkh]     = wp[0];
        *(uint4*)&Bs[lr][lkh + 8] = wp[1];
        __syncthreads();
        bf16x8 af[4], bfr[4];
        #pragma unroll
        for (int t = 0; t < 4; ++t) af[t]  = *(const bf16x8*)&As[wr * 64 + t * 16 + m16][quad * 8];
        #pragma unroll
        for (int t = 0; t < 4; ++t) bfr[t] = *(const bf16x8*)&Bs[wc * 64 + t * 16 + m16][quad * 8];
        #pragma unroll
        for (int i = 0; i < 4; ++i)
            #pragma unroll
            for (int j = 0; j < 4; ++j)
                acc[i][j] = __builtin_amdgcn_mfma_f32_16x16x32_bf16(af[i], bfr[j], acc[i][j], 0, 0, 0);
        __syncthreads();
    }

    const float* bias = (y == 0) ? bq : (y == 1) ? bk : (y == 2) ? bv : bf;

    if (y == 1 || y == 2) {
        // k/v in fp8 e4m3 (OCP): HW pack, single-byte stores into the
        // interleaved kv8 row ([0,128)=K, [128,256)=V)
        const int ocol = (y == 2) ? 128 : 0;
        #pragma unroll
        for (int i = 0; i < 4; ++i)
            #pragma unroll
            for (int j = 0; j < 4; ++j) {
                const int col = wc * 64 + j * 16 + m16;
                const float b = bias[col];
                #pragma unroll
                for (int r = 0; r < 4; ++r) {
                    const int row = row0 + wr * 64 + i * 16 + quad * 4 + r;
                    if (row < M) {
                        const unsigned int pk =
                            (unsigned int)__builtin_amdgcn_cvt_pk_fp8_f32(acc[i][j][r] + b, 0.f, 0, 0);
                        kv8[(size_t)row * 256 + ocol + col] = (unsigned char)(pk & 0xFF);
                    }
                }
            }
    } else {
        unsigned short* obase = (y == 3) ? ffnb : qb;
        #pragma unroll
        for (int i = 0; i < 4; ++i)
            #pragma unroll
            for (int j = 0; j < 4; ++j) {
                const int col = wc * 64 + j * 16 + m16;
                const float b = bias[col];
                #pragma unroll
                for (int r = 0; r < 4; ++r) {
                    const int row = row0 + wr * 64 + i * 16 + quad * 4 + r;
                    if (row < M) obase[(size_t)row * 128 + col] = f2bf(acc[i][j][r] + b);
                }
            }
    }
}

// ---------------------------------------------------------------------------
// Pass 1: bin edges into NB buckets of 256 nodes. Stage record:
// x = f32 feat bits, y = (src << 8) | (nid & 255).
// ---------------------------------------------------------------------------
__global__ __launch_bounds__(256) void binpass_k(
    const int* __restrict__ dst0, const int* __restrict__ dst1,
    const int* __restrict__ src0, const int* __restrict__ src1,
    const float* __restrict__ feat0, const float* __restrict__ feat1,
    int* __restrict__ cursor, uint2* __restrict__ stage)
{
    __shared__ int hcnt[NB], blkbase[NB], lcur[NB];
    const int tid = threadIdx.x;
    const long base = (long)blockIdx.x * 8192;

    for (int i = tid; i < NB; i += 256) { hcnt[i] = 0; lcur[i] = 0; }
    __syncthreads();

    for (int i = tid; i < 8192; i += 256) {
        const long e = base + i;
        if (e < 2L * EE) {
            const int nid = (e < EE) ? dst0[e] : NN + dst1[e - EE];
            atomicAdd(&hcnt[nid >> 8], 1);
        }
    }
    __syncthreads();
    for (int i = tid; i < NB; i += 256)
        if (hcnt[i]) blkbase[i] = atomicAdd(&cursor[i], hcnt[i]);
    __syncthreads();

    for (int i = tid; i < 8192; i += 256) {
        const long e = base + i;
        if (e < 2L * EE) {
            const bool a = (e < EE);
            const int ee = a ? (int)e : (int)(e - EE);
            const int nid = a ? dst0[ee] : NN + dst1[ee];
            const int s = a ? src0[ee] : src1[ee];
            const float f = a ? feat0[(size_t)ee * 2] : feat1[(size_t)ee * 2];
            const int bk = nid >> 8;
            const int r = atomicAdd(&lcur[bk], 1);
            uint2 rec;
            rec.x = __float_as_uint(f);
            rec.y = ((unsigned int)s << 8) | (unsigned int)(nid & 255);
            stage[(size_t)bk * CAP + blkbase[bk] + r] = rec;
        }
    }
}

__global__ __launch_bounds__(512) void bscan_k(const int* __restrict__ cursor, int* __restrict__ bbase)
{
    __shared__ int part[512];
    const int t = threadIdx.x;
    const int v = (t < NB) ? cursor[t] : 0;
    part[t] = v;
    __syncthreads();
    for (int st = 1; st < 512; st <<= 1) {
        int u = (t >= st) ? part[t - st] : 0;
        __syncthreads();
        part[t] += u;
        __syncthreads();
    }
    if (t < NB) bbase[t] = part[t] - v;
}

// ---------------------------------------------------------------------------
// Pass 2: one block per bucket. Records staged once into LDS (40 KB), then
// histogram + scatter run from LDS (removes the second 12.8 MB global read).
// Emits PACKED erec word: (src << 15) | round(feat * 32767)  [src < 2^17,
// feat in [0,1) -> 15-bit fixed point, quant err ~3e-5] plus off/deg.
// ---------------------------------------------------------------------------
__global__ __launch_bounds__(256) void sortpass_k(
    const uint2* __restrict__ stage, const int* __restrict__ cursor,
    const int* __restrict__ bbase, unsigned int* __restrict__ erec,
    int* __restrict__ off, int* __restrict__ deg)
{
    __shared__ uint2 srec[CAP];
    __shared__ int h[256], eb[256], cur[256];
    const int b = blockIdx.x;
    const int t = threadIdx.x;
    const int cntb = min(cursor[b], CAP);
    const int obase = bbase[b];
    const uint2* sb = stage + (size_t)b * CAP;

    h[t] = 0; cur[t] = 0;
    for (int i = t; i < cntb; i += 256) srec[i] = sb[i];
    __syncthreads();
    for (int i = t; i < cntb; i += 256) atomicAdd(&h[(int)(srec[i].y & 255u)], 1);
    __syncthreads();
    eb[t] = h[t];
    __syncthreads();
    for (int st = 1; st < 256; st <<= 1) {
        int u = (t >= st) ? eb[t - st] : 0;
        __syncthreads();
        eb[t] += u;
        __syncthreads();
    }
    const int incl = eb[t];
    __syncthreads();
    eb[t] = incl - h[t];          // exclusive
    __syncthreads();

    const int nid = b * 256 + t;
    if (nid < NTOT) {
        off[nid] = obase + eb[t];
        deg[nid] = h[t];
    }

    for (int i = t; i < cntb; i += 256) {
        const uint2 r = srec[i];
        const int loc = (int)(r.y & 255u);
        const int rk = atomicAdd(&cur[loc], 1);
        const unsigned int f15 = __float2uint_rn(__uint_as_float(r.x) * 32767.f);
        erec[obase + eb[loc] + rk] = ((r.y >> 8) << 15) | f15;
    }
}

// ---------------------------------------------------------------------------
// Aggregation, both edge sets in one dispatch: one wave per combined node id.
// Lane layout: g = lane>>4 is the edge slot (4 edges in flight per wave),
// d16 = lane&15 owns dims [d16*8, d16*8+8). K and V both fp8 e4m3 in ONE
// interleaved 256B row ([0,128)=K, [128,256)=V): per edge one base address,
// two 8B loads (V at +128 imm). erec is PACKED (src<<15 | feat15) -> one
// shuffle per iteration delivers both src and feat. q bf16 (256B/row).
// HW pair-decode (v_cvt_pk_f32_fp8) + f32x2 vector math. Head reduce =
// 2 shfl_xor; score stays lane-resident for V accumulation; cross-slot
// combine in the epilogue.
// ---------------------------------------------------------------------------
__global__ __launch_bounds__(256) void aggregate_k(
    const unsigned short* __restrict__ qb, const unsigned char* __restrict__ kv8,
    const unsigned int* __restrict__ erec,
    const int* __restrict__ off, const int* __restrict__ deg,
    unsigned short* __restrict__ att)
{
    const int nid = blockIdx.x * 4 + (threadIdx.x >> 6);
    if (nid >= NTOT) return;
    const int n = (nid >= NN) ? nid - NN : nid;
    const int lane = threadIdx.x & 63;
    const int g   = lane >> 4;     // edge slot 0..3
    const int d16 = lane & 15;     // dim-block: dims [d16*8, d16*8+8)
    const int start = off[nid];
    const int count = deg[nid];

    // q: my 8 dims, bf16 -> f32x2 pairs (dims 2i, 2i+1)
    const uint4 qu = *(const uint4*)(qb + (size_t)n * 128 + d16 * 8);
    f32x2 qd0, qd1, qd2, qd3;
    qd0[0] = bflo(qu.x); qd0[1] = bfhi(qu.x);
    qd1[0] = bflo(qu.y); qd1[1] = bfhi(qu.y);
    qd2[0] = bflo(qu.z); qd2[1] = bfhi(qu.z);
    qd3[0] = bflo(qu.w); qd3[1] = bfhi(qu.w);

    f32x2 av0 = 0.f, av1 = 0.f, av2 = 0.f, av3 = 0.f;
    float zp = 0.f;
    const float SCALE = 0.088388347648318447f;  // 1/sqrt(128)
    const float FDEQ  = 1.0f / 32767.0f;
    const unsigned char* kvl = kv8 + d16 * 8;   // lane-fixed dim offset

    for (int base = 0; base < count; base += 64) {
        const int m = min(64, count - base);
        const unsigned int ue = erec[start + base + min(lane, m - 1)];
        // prefetch batch 0 (dead slots read the clamped record: valid addr)
        unsigned int cu = (unsigned int)__shfl((int)ue, g);
        const unsigned char* rp = kvl + (size_t)(cu >> 15) * 256;
        uint2 kc = *(const uint2*)rp;
        uint2 vc = *(const uint2*)(rp + 128);
        for (int j0 = 0; j0 < m; j0 += 4) {
            const uint2 kk = kc;
            const uint2 vv = vc;
            const float f = (float)(cu & 32767u) * FDEQ;
            const int jn = j0 + 4;
            if (jn < m) {      // uniform branch: prefetch next batch
                cu = (unsigned int)__shfl((int)ue, jn + g);
                const unsigned char* rn = kvl + (size_t)(cu >> 15) * 256;
                kc = *(const uint2*)rn;
                vc = *(const uint2*)(rn + 128);
            }
            // decode 8 fp8 k dims (4 HW pair-converts), packed dot with q
            const f32x2 k0 = __builtin_amdgcn_cvt_pk_f32_fp8((int)kk.x, false);
            const f32x2 k1 = __builtin_amdgcn_cvt_pk_f32_fp8((int)kk.x, true);
            const f32x2 k2 = __builtin_amdgcn_cvt_pk_f32_fp8((int)kk.y, false);
            const f32x2 k3 = __builtin_amdgcn_cvt_pk_f32_fp8((int)kk.y, true);
            f32x2 p2 = k0 * qd0;
            p2 += k1 * qd1;
            p2 += k2 * qd2;
            p2 += k3 * qd3;
            float p = p2[0] + p2[1];
            // head reduce: 4 lanes (d16 within the same head) = 32 dims
            p += __shfl_xor(p, 1);
            p += __shfl_xor(p, 2);
            float sc = __expf(fminf(5.f, fmaxf(-5.f, p * f * SCALE)));
            sc = (j0 + g < m) ? sc : 0.f;
            zp += sc;          // per-lane: my head's z over my slot's edges
            // decode 8 fp8 v dims, packed weighted accumulate
            const f32x2 v0 = __builtin_amdgcn_cvt_pk_f32_fp8((int)vv.x, false);
            const f32x2 v1 = __builtin_amdgcn_cvt_pk_f32_fp8((int)vv.x, true);
            const f32x2 v2 = __builtin_amdgcn_cvt_pk_f32_fp8((int)vv.y, false);
            const f32x2 v3 = __builtin_amdgcn_cvt_pk_f32_fp8((int)vv.y, true);
            f32x2 sc2; sc2[0] = sc; sc2[1] = sc;
            av0 += v0 * sc2;
            av1 += v1 * sc2;
            av2 += v2 * sc2;
            av3 += v3 * sc2;
        }
    }

    // combine the 4 edge slots (lane bits 4,5)
    float z = zp;
    z += __shfl_xor(z, 16);
    z += __shfl_xor(z, 32);
    av0[0] += __shfl_xor(av0[0], 16); av0[0] += __shfl_xor(av0[0], 32);
    av0[1] += __shfl_xor(av0[1], 16); av0[1] += __shfl_xor(av0[1], 32);
    av1[0] += __shfl_xor(av1[0], 16); av1[0] += __shfl_xor(av1[0], 32);
    av1[1] += __shfl_xor(av1[1], 16); av1[1] += __shfl_xor(av1[1], 32);
    av2[0] += __shfl_xor(av2[0], 16); av2[0] += __shfl_xor(av2[0], 32);
    av2[1] += __shfl_xor(av2[1], 16); av2[1] += __shfl_xor(av2[1], 32);
    av3[0] += __shfl_xor(av3[0], 16); av3[0] += __shfl_xor(av3[0], 32);
    av3[1] += __shfl_xor(av3[1], 16); av3[1] += __shfl_xor(av3[1], 32);

    const float inv = 1.f / (z + 1.f);   // per-head z (head = d16>>2)
    // slot g writes dims d16*8 + 2g, 2g+1 = av<g> (static selects, no scratch)
    const f32x2 e01 = (g & 1) ? av1 : av0;
    const f32x2 e23 = (g & 1) ? av3 : av2;
    const f32x2 e   = (g & 2) ? e23 : e01;
    const float ax = e[0] * inv;
    const float ay = e[1] * inv;
    const unsigned int o = ((unsigned int)f2bf(ay) << 16) | (unsigned int)f2bf(ax);
    *(unsigned int*)(att + (size_t)nid * 128 + d16 * 8 + g * 2) = o;
}

// ---------------------------------------------------------------------------
// Output GEMM, XCD-swizzled 1D grid (8 * RPX * 2 blocks): the 2 set-tiles of
// one row tile are id-adjacent on the SAME XCD -> the shared ffnb row panel
// L2-caches (read once instead of twice). LN epilogue in fp32 registers.
// ---------------------------------------------------------------------------
__global__ __launch_bounds__(256) void attn_out_mfma_k(
    const unsigned short* __restrict__ attAll, const unsigned short* __restrict__ Wt,
    const float* __restrict__ bo, const unsigned short* __restrict__ ffnb,
    const float* __restrict__ g, const float* __restrict__ bln,
    float* __restrict__ Yall, int M)
{
    const int nblk = blockIdx.x;
    const int xcd  = nblk & 7;
    const int slot = nblk >> 3;
    const int rowt = xcd * RPX + (slot >> 1);
    const int set  = slot & 1;
    if (rowt >= MT) return;

    __shared__ unsigned short As[128][40];
    __shared__ unsigned short Bs[128][40];
    __shared__ float rsum[2][128], rsq[2][128];
    __shared__ float meanar[128], invar[128];

    const unsigned short* att = attAll + (size_t)set * NN * 128;
    float* Y = Yall + (size_t)set * NN * 128;

    const int tid  = threadIdx.x;
    const int lane = tid & 63;
    const int wave = tid >> 6;
    const int wr = wave >> 1, wc = wave & 1;
    const int quad = lane >> 4, m16 = lane & 15;
    const int row0 = rowt * 128;

    f32x4 acc[4][4];
    #pragma unroll
    for (int i = 0; i < 4; ++i)
        #pragma unroll
        for (int j = 0; j < 4; ++j) acc[i][j] = 0.f;

    const int lr  = tid >> 1;
    const int lkh = (tid & 1) * 16;

    for (int kt = 0; kt < 128; kt += 32) {
        uint4 a0 = {0,0,0,0}, a1 = {0,0,0,0};
        const int grow = row0 + lr;
        if (grow < M) {
            const uint4* p = (const uint4*)(att + (size_t)grow * 128 + kt + lkh);
            a0 = p[0]; a1 = p[1];
        }
        *(uint4*)&As[lr][lkh]     = a0;
        *(uint4*)&As[lr][lkh + 8] = a1;
        const uint4* wp = (const uint4*)(Wt + (size_t)lr * 128 + kt + lkh);
        *(uint4*)&Bs[lr][lkh]     = wp[0];
        *(uint4*)&Bs[lr][lkh + 8] = wp[1];
        __syncthreads();
        bf16x8 af[4], bfr[4];
        #pragma unroll
        for (int t = 0; t < 4; ++t) af[t]  = *(const bf16x8*)&As[wr * 64 + t * 16 + m16][quad * 8];
        #pragma unroll
        for (int t = 0; t < 4; ++t) bfr[t] = *(const bf16x8*)&Bs[wc * 64 + t * 16 + m16][quad * 8];
        #pragma unroll
        for (int i = 0; i < 4; ++i)
            #pragma unroll
            for (int j = 0; j < 4; ++j)
                acc[i][j] = __builtin_amdgcn_mfma_f32_16x16x32_bf16(af[i], bfr[j], acc[i][j], 0, 0, 0);
        __syncthreads();
    }

    // ah = C + bo + ffn (fp32 in regs); per-row partial sums
    #pragma unroll
    for (int i = 0; i < 4; ++i) {
        #pragma unroll
        for (int r = 0; r < 4; ++r) {
            const int rl = wr * 64 + i * 16 + quad * 4 + r;
            const int grow = row0 + rl;
            float s = 0.f, q = 0.f;
            #pragma unroll
            for (int j = 0; j < 4; ++j) {
                const int col = wc * 64 + j * 16 + m16;
                float v = acc[i][j][r] + bo[col];
                if (grow < M) v += bflo(ffnb[(size_t)grow * 128 + col]);
                acc[i][j][r] = v;
                s += v; q += v * v;
            }
            #pragma unroll
            for (int mm = 1; mm <= 8; mm <<= 1) {
                s += __shfl_xor(s, mm, 16);
                q += __shfl_xor(q, mm, 16);
            }
            if (m16 == 0) { rsum[wc][rl] = s; rsq[wc][rl] = q; }
        }
    }
    __syncthreads();
    if (tid < 128) {
        const float s = rsum[0][tid] + rsum[1][tid];
        const float q = rsq[0][tid] + rsq[1][tid];
        const float mean = s * (1.f / 128.f);
        const float var  = q * (1.f / 128.f) - mean * mean;
        meanar[tid] = mean;
        invar[tid]  = rsqrtf(fmaxf(var, 0.f) + 1e-5f);
    }
    __syncthreads();

    #pragma unroll
    for (int i = 0; i < 4; ++i) {
        #pragma unroll
        for (int j = 0; j < 4; ++j) {
            const int col = wc * 64 + j * 16 + m16;
            const float gv = g[col], lv = bln[col];
            #pragma unroll
            for (int r = 0; r < 4; ++r) {
                const int rl = wr * 64 + i * 16 + quad * 4 + r;
                const int grow = row0 + rl;
                if (grow < M) {
                    const float v = acc[i][j][r];
                    Y[(size_t)grow * 128 + col] = v + (v - meanar[rl]) * invar[rl] * gv + lv;
                }
            }
        }
    }
}

// ---------------------------------------------------------------------------
extern "C" void kernel_launch(void* const* d_in, const int* in_sizes, int n_in,
                              void* d_out, int out_size, void* d_ws, size_t ws_size,
                              hipStream_t stream) {
    const float* x99   = (const float*)d_in[2];
    const float* feat0 = (const float*)d_in[3];
    const float* feat1 = (const float*)d_in[4];
    const float* Waq   = (const float*)d_in[10];
    const float* Wak   = (const float*)d_in[11];
    const float* Wav   = (const float*)d_in[12];
    const float* Wao   = (const float*)d_in[13];
    const float* Waffn = (const float*)d_in[14];
    const float* baq   = (const float*)d_in[20];
    const float* bak   = (const float*)d_in[21];
    const float* bav   = (const float*)d_in[22];
    const float* bao   = (const float*)d_in[23];
    const float* baffn = (const float*)d_in[24];
    const float* aln_b = (const float*)d_in[26];
    const float* aln_g = (const float*)d_in[28];
    const int* src0 = (const int*)d_in[29];
    const int* dst0 = (const int*)d_in[30];
    const int* src1 = (const int*)d_in[31];
    const int* dst1 = (const int*)d_in[32];

    // workspace (~103 MB)
    unsigned short* xb   = (unsigned short*)d_ws;                 // NN*256 us
    unsigned short* qb   = xb + (size_t)NN * 256;                 // NN*128 us
    unsigned char*  kv8  = (unsigned char*)(qb + (size_t)NN * 128);   // NN*256 bytes
    unsigned short* ffnb = (unsigned short*)(kv8 + (size_t)NN * 256); // NN*128 us
    unsigned short* att  = ffnb + (size_t)NN * 128;               // 2*NN*128 us
    unsigned short* Wt   = att  + (size_t)NTOT * 128;             // 512*256 us
    unsigned short* Waot = Wt   + (size_t)512 * 256;              // 128*128 us
    int* cursor = (int*)(Waot + 128 * 128);                       // NB
    int* bbase  = cursor + NB;                                    // NB
    int* off    = bbase + NB;                                     // NTOT
    int* deg    = off + NTOT;                                     // NTOT

    float* out = (float*)d_out;
    // stage (16.0 MB) + erec (6.4 MB, packed uint) parked in d_out; both are
    // fully consumed (sortpass, aggregate) before attn_out writes d_out.
    uint2* stage = (uint2*)d_out;                                 // NB*CAP
    unsigned int* erec = (unsigned int*)(stage + (size_t)NB * CAP);   // 2*EE

    cvt_x_k<<<(NN * AIN / 4 + 255) / 256, 256, 0, stream>>>(x99, xb);
    cvt_w_k<<<640, 256, 0, stream>>>(Waq, Wak, Wav, Waffn, Wao, Wt, Waot);

    qkvf_mfma_k<<<8 * RPX * 4, 256, 0, stream>>>(xb, Wt, baq, bak, bav, baffn, qb, kv8, ffnb, NN);

    hipMemsetAsync(cursor, 0, NB * sizeof(int), stream);
    binpass_k<<<(2 * EE + 8191) / 8192, 256, 0, stream>>>(
        dst0, dst1, src0, src1, feat0, feat1, cursor, stage);
    bscan_k<<<1, 512, 0, stream>>>(cursor, bbase);
    sortpass_k<<<NB, 256, 0, stream>>>(stage, cursor, bbase, erec, off, deg);

    aggregate_k<<<(NTOT + 3) / 4, 256, 0, stream>>>(qb, kv8, erec, off, deg, att);
    attn_out_mfma_k<<<8 * RPX * 2, 256, 0, stream>>>(att, Waot, bao, ffnb, aln_g, aln_b, out, NN);
}